// Round 10
// baseline (481.632 us; speedup 1.0000x reference)
//
#include <hip/hip_runtime.h>
#include <math.h>

#define EPSV   1e-5f
#define SLOPE  0.2f

#define B_   2
#define N_   2048
#define M_   64
#define C_   128
#define C2_  256
#define H_   128
#define O_   64

typedef short  s16x8  __attribute__((ext_vector_type(8)));
typedef ushort u16x8  __attribute__((ext_vector_type(8)));
typedef float  f32x16 __attribute__((ext_vector_type(16)));

#define ZERO16 {0.f,0.f,0.f,0.f,0.f,0.f,0.f,0.f,0.f,0.f,0.f,0.f,0.f,0.f,0.f,0.f}

// ---------------- workspace (float offsets) ----------------
#define WS_H1      0            // [4096*128]
#define WS_HC      524288       // [128*128]
#define WS_PMAX    540672       // [4096*256]
#define WS_PMIN    1589248      // [4096*256]
#define WS_W2BF    2637824      // 256*128 bf16
#define WS_W3BF    2654208      // 256*256 bf16
#define WS_SUMA    2686976      // [2*128]
#define WS_SSQA    2687232
#define WS_SUMC    2687488
#define WS_SSQC    2687744
#define WS_SUM2    2688000      // [256]
#define WS_SSQ2    2688256
#define WS_SUM3    2688512
#define WS_SSQ3    2688768
#define WS_SUM4    2689024      // [128]
#define WS_SSQ4    2689152
#define WS_SUM5    2689280      // [64]
#define WS_SSQ5    2689344
#define WS_ZERO_BEG WS_SUMA
#define WS_ZERO_CNT (2689408 - WS_SUMA)
#define WS_X4      WS_H1        // reuse (H1 dead after k_x3f)
#define WS_X5      WS_PMIN      // reuse (PMIN dead after k_fc1)

#define CNT1  ((float)B_ * N_ * M_)
#define CNT45 ((float)B_ * N_)

__device__ inline ushort f2b(float x) {
  unsigned u = __builtin_bit_cast(unsigned, x);
  u += 0x7fffu + ((u >> 16) & 1u);
  return (ushort)(u >> 16);
}
__device__ inline float lrelu(float x) { return fmaxf(x, SLOPE * x); }

// ---------------- W -> bf16 ----------------
__global__ __launch_bounds__(256) void k_cvtW(const float* __restrict__ W2,
                                              const float* __restrict__ W3,
                                              ushort* __restrict__ w2b,
                                              ushort* __restrict__ w3b) {
  int i = blockIdx.x * 256 + threadIdx.x;
  if (i < C2_ * C_) w2b[i] = f2b(W2[i]);
  w3b[i] = f2b(W3[i]);
}

// ---------------- projections, 4 rows/block ----------------
__global__ __launch_bounds__(128) void k_proj4(const float* __restrict__ x,
                                               const float* __restrict__ W1,
                                               float* __restrict__ out, int col_off) {
  __shared__ float xs[4][C_];
  int row0 = blockIdx.x * 4, t = threadIdx.x;
#pragma unroll
  for (int r = 0; r < 4; ++r) xs[r][t] = x[(row0 + r) * C_ + t];
  __syncthreads();
  const float* w = W1 + t * (2 * C_) + col_off;
  float acc[4] = {0.f, 0.f, 0.f, 0.f};
  for (int c = 0; c < C_; c += 4) {
    float4 wv = *(const float4*)(w + c);
#pragma unroll
    for (int r = 0; r < 4; ++r) {
      float4 xv = *(const float4*)(&xs[r][c]);
      acc[r] = fmaf(wv.x, xv.x, fmaf(wv.y, xv.y, fmaf(wv.z, xv.z, fmaf(wv.w, xv.w, acc[r]))));
    }
  }
#pragma unroll
  for (int r = 0; r < 4; ++r) out[(row0 + r) * C_ + t] = acc[r];
}

// ---------------- coalesced per-(b,c) row stats ----------------
__global__ __launch_bounds__(256) void k_rowstats(const float* __restrict__ x,
                                                  float* __restrict__ sums,
                                                  float* __restrict__ ssqs,
                                                  int rows_per_b) {
  __shared__ float red[256];
  int t = threadIdx.x, c = t & 127, rr = t >> 7;
  int r0 = blockIdx.x * 32, b = r0 / rows_per_b;
  float s = 0.f, s2 = 0.f;
  for (int i = 0; i < 16; ++i) {
    float v = x[(r0 + rr + i * 2) * C_ + c];
    s += v; s2 = fmaf(v, v, s2);
  }
  red[t] = s;
  __syncthreads();
  if (t < 128) atomicAdd(&sums[b * C_ + t], red[t] + red[t + 128]);
  __syncthreads();
  red[t] = s2;
  __syncthreads();
  if (t < 128) atomicAdd(&ssqs[b * C_ + t], red[t] + red[t + 128]);
}

// ---------------- build S1 tile (inline bn1 params) ----------------
// S1 ushort idx: r*128 + ((j ^ (r&15))<<3) + (c&7),  j = c>>3
__device__ inline void build_S1_256(ushort* S1, const float* __restrict__ h1,
                                    const float* __restrict__ hc,
                                    const float* __restrict__ sumA,
                                    const float* __restrict__ ssqA,
                                    const float* __restrict__ sumC,
                                    const float* __restrict__ ssqC,
                                    const float* __restrict__ g1,
                                    const float* __restrict__ b1,
                                    int nf0, int b,
                                    float (*h1s)[C_], float* sc1, float* sh1) {
  int t = threadIdx.x;
  h1s[t >> 7][t & 127] = h1[(nf0 + (t >> 7)) * C_ + (t & 127)];
  if (t < C_) {
    int c = t;
    float sA0 = sumA[c], sA1 = sumA[C_ + c], qA0 = ssqA[c], qA1 = ssqA[C_ + c];
    float sC0 = sumC[c], sC1 = sumC[C_ + c], qC0 = ssqC[c], qC1 = ssqC[C_ + c];
    float mean = ((float)M_ * (sA0 + sA1) + (float)N_ * (sC0 + sC1)) / CNT1;
    float ex2 = ((float)M_ * (qA0 + qA1) + (float)N_ * (qC0 + qC1)
                 + 2.f * (sA0 * sC0 + sA1 * sC1)) / CNT1;
    float var = ex2 - mean * mean;
    float sc = g1[c] * rsqrtf(var + EPSV);
    sc1[c] = sc;
    sh1[c] = b1[c] - mean * sc;
  }
  __syncthreads();
  const float* hcb = hc + b * M_ * C_;
#pragma unroll
  for (int i = 0; i < 8; ++i) {
    int s = t + i * 512;
    int r = s >> 4, j = s & 15, c0 = j << 3;
    const float* hr = h1s[r >> 6];
    const float* src = hcb + (r & 63) * C_ + c0;
    float4 v0 = *(const float4*)(src);
    float4 v1 = *(const float4*)(src + 4);
    u16x8 q;
    q[0] = f2b(lrelu(fmaf(sc1[c0+0], hr[c0+0] + v0.x, sh1[c0+0])));
    q[1] = f2b(lrelu(fmaf(sc1[c0+1], hr[c0+1] + v0.y, sh1[c0+1])));
    q[2] = f2b(lrelu(fmaf(sc1[c0+2], hr[c0+2] + v0.z, sh1[c0+2])));
    q[3] = f2b(lrelu(fmaf(sc1[c0+3], hr[c0+3] + v0.w, sh1[c0+3])));
    q[4] = f2b(lrelu(fmaf(sc1[c0+4], hr[c0+4] + v1.x, sh1[c0+4])));
    q[5] = f2b(lrelu(fmaf(sc1[c0+5], hr[c0+5] + v1.y, sh1[c0+5])));
    q[6] = f2b(lrelu(fmaf(sc1[c0+6], hr[c0+6] + v1.z, sh1[c0+6])));
    q[7] = f2b(lrelu(fmaf(sc1[c0+7], hr[c0+7] + v1.w, sh1[c0+7])));
    *(u16x8*)(S1 + r * C_ + ((j ^ (r & 15)) << 3)) = q;
  }
  __syncthreads();
}

// ---------------- pass B: stats of X2 (32x32x16, 2x2-acc, fits 128 VGPR) ----------------
__global__ __launch_bounds__(512, 2) void k_x2f(const float* __restrict__ h1,
                                                const float* __restrict__ hc,
                                                const float* __restrict__ sumA,
                                                const float* __restrict__ ssqA,
                                                const float* __restrict__ sumC,
                                                const float* __restrict__ ssqC,
                                                const float* __restrict__ g1v,
                                                const float* __restrict__ b1v,
                                                const ushort* __restrict__ W2b,
                                                float* __restrict__ sum2,
                                                float* __restrict__ ssq2) {
  __shared__ __align__(16) ushort S1[256 * C_];   // 64 KB
  __shared__ float h1s[4][C_], sc1[C_], sh1[C_];
  int nf0 = blockIdx.x * 4, b = nf0 >> 11;
  build_S1_256(S1, h1, hc, sumA, ssqA, sumC, ssqC, g1v, b1v, nf0, b, h1s, sc1, sh1);
  int t = threadIdx.x, wv = t >> 6, lane = t & 63, l31 = lane & 31, l5 = lane >> 5;
  int RG = wv >> 2, OB = (wv & 3) * 64;

  const ushort* w2r0 = W2b + (OB + l31) * C_ + l5 * 8;
  const ushort* w2r1 = w2r0 + 32 * C_;
  float sm0 = 0.f, sq0 = 0.f, sm1 = 0.f, sq1 = 0.f;

#pragma unroll 1
  for (int h = 0; h < 2; ++h) {
    f32x16 acc00 = ZERO16, acc01 = ZERO16, acc10 = ZERO16, acc11 = ZERO16;
    int r0 = RG * 128 + h * 64 + l31, r1 = r0 + 32;
    const ushort* s1r0 = S1 + r0 * C_;
    const ushort* s1r1 = S1 + r1 * C_;
    int rx0 = r0 & 15, rx1 = r1 & 15;
#pragma unroll
    for (int ks = 0; ks < 8; ++ks) {
      int j = ks * 2 + l5;
      s16x8 b0 = *(const s16x8*)(w2r0 + ks * 16);
      s16x8 b1 = *(const s16x8*)(w2r1 + ks * 16);
      s16x8 a0 = *(const s16x8*)(s1r0 + ((j ^ rx0) << 3));
      s16x8 a1 = *(const s16x8*)(s1r1 + ((j ^ rx1) << 3));
      acc00 = __builtin_amdgcn_mfma_f32_32x32x16_bf16(a0, b0, acc00, 0, 0, 0);
      acc01 = __builtin_amdgcn_mfma_f32_32x32x16_bf16(a0, b1, acc01, 0, 0, 0);
      acc10 = __builtin_amdgcn_mfma_f32_32x32x16_bf16(a1, b0, acc10, 0, 0, 0);
      acc11 = __builtin_amdgcn_mfma_f32_32x32x16_bf16(a1, b1, acc11, 0, 0, 0);
    }
#pragma unroll
    for (int rg = 0; rg < 16; ++rg) {
      float v;
      v = acc00[rg]; sm0 += v; sq0 = fmaf(v, v, sq0);
      v = acc10[rg]; sm0 += v; sq0 = fmaf(v, v, sq0);
      v = acc01[rg]; sm1 += v; sq1 = fmaf(v, v, sq1);
      v = acc11[rg]; sm1 += v; sq1 = fmaf(v, v, sq1);
    }
  }
  sm0 += __shfl_xor(sm0, 32); sq0 += __shfl_xor(sq0, 32);
  sm1 += __shfl_xor(sm1, 32); sq1 += __shfl_xor(sq1, 32);
  if (lane < 32) {
    atomicAdd(&sum2[OB + l31], sm0);
    atomicAdd(&ssq2[OB + l31], sq0);
    atomicAdd(&sum2[OB + 32 + l31], sm1);
    atomicAdd(&ssq2[OB + 32 + l31], sq1);
  }
}

// ---------------- pass C: stage2 + stage3 + pool (32x32x16, fat acc, 256-VGPR budget) ----
// LDS 136 KB -> 1 block/CU regardless; (512,1) unlocks 256 VGPRs so the
// R8 4-acc structure fits WITHOUT spill (R8's regression was the 128 cap).
// S2 ushort idx: r*256 + ((j3 ^ (r&31))<<3) + (o&7), j3 = o>>3
__global__ __launch_bounds__(512, 1) void k_x3f(const float* __restrict__ h1,
                                                const float* __restrict__ hc,
                                                const float* __restrict__ sumA,
                                                const float* __restrict__ ssqA,
                                                const float* __restrict__ sumC,
                                                const float* __restrict__ ssqC,
                                                const float* __restrict__ g1v,
                                                const float* __restrict__ b1v,
                                                const ushort* __restrict__ W2b,
                                                const float* __restrict__ sum2,
                                                const float* __restrict__ ssq2,
                                                const float* __restrict__ g2v,
                                                const float* __restrict__ b2v,
                                                const ushort* __restrict__ W3b,
                                                float* __restrict__ sum3,
                                                float* __restrict__ ssq3,
                                                float* __restrict__ Pmax,
                                                float* __restrict__ Pmin) {
  __shared__ __align__(16) ushort S1[256 * C_];    // 64 KB
  __shared__ __align__(16) ushort S2[128 * C2_];   // 64 KB (one 128-row half)
  __shared__ float h1s[4][C_], sc1[C_], sh1[C_];
  __shared__ float sc2s[C2_], sh2s[C2_];
  int nf0 = blockIdx.x * 4, b = nf0 >> 11;
  int t = threadIdx.x;
  if (t < C2_) {   // inline bn2 params (sum2/ssq2 complete at kernel boundary)
    float mean = sum2[t] / CNT1;
    float var = ssq2[t] / CNT1 - mean * mean;
    float sc = g2v[t] * rsqrtf(var + EPSV);
    sc2s[t] = sc;
    sh2s[t] = b2v[t] - mean * sc;
  }
  build_S1_256(S1, h1, hc, sumA, ssqA, sumC, ssqC, g1v, b1v, nf0, b, h1s, sc1, sh1);
  int wv = t >> 6, lane = t & 63, l31 = lane & 31, l5 = lane >> 5;
  int RG = wv >> 2, OB = (wv & 3) * 64, LB = RG * 64;

  int colA = OB + l31, colB = colA + 32;
  const ushort* w2r0 = W2b + colA * C_ + l5 * 8;
  const ushort* w2r1 = W2b + colB * C_ + l5 * 8;
  const ushort* w3r0 = W3b + colA * C2_ + l5 * 8;
  const ushort* w3r1 = W3b + colB * C2_ + l5 * 8;
  int jA = colA >> 3, jB = colB >> 3, olow = lane & 7;

  float sm0 = 0.f, sq0 = 0.f, sm1 = 0.f, sq1 = 0.f;

#pragma unroll 1
  for (int h = 0; h < 2; ++h) {
    // ---- stage 2: 64 rows (2 x 32-tiles) x 64 o -> S2
    {
      f32x16 acc00 = ZERO16, acc01 = ZERO16, acc10 = ZERO16, acc11 = ZERO16;
      int r0 = RG * 128 + h * 64 + l31, r1 = r0 + 32;
      const ushort* s1r0 = S1 + r0 * C_;
      const ushort* s1r1 = S1 + r1 * C_;
      int rx0 = r0 & 15, rx1 = r1 & 15;
#pragma unroll
      for (int ks = 0; ks < 8; ++ks) {
        int j = ks * 2 + l5;
        s16x8 b0 = *(const s16x8*)(w2r0 + ks * 16);
        s16x8 b1 = *(const s16x8*)(w2r1 + ks * 16);
        s16x8 a0 = *(const s16x8*)(s1r0 + ((j ^ rx0) << 3));
        s16x8 a1 = *(const s16x8*)(s1r1 + ((j ^ rx1) << 3));
        acc00 = __builtin_amdgcn_mfma_f32_32x32x16_bf16(a0, b0, acc00, 0, 0, 0);
        acc01 = __builtin_amdgcn_mfma_f32_32x32x16_bf16(a0, b1, acc01, 0, 0, 0);
        acc10 = __builtin_amdgcn_mfma_f32_32x32x16_bf16(a1, b0, acc10, 0, 0, 0);
        acc11 = __builtin_amdgcn_mfma_f32_32x32x16_bf16(a1, b1, acc11, 0, 0, 0);
      }
      float scA = sc2s[colA], shA = sh2s[colA];
      float scB = sc2s[colB], shB = sh2s[colB];
#pragma unroll
      for (int rg = 0; rg < 16; ++rg) {
        int rp = (rg & 3) + 8 * (rg >> 2) + 4 * l5;
        int m0 = LB + rp, m1 = m0 + 32;
        S2[m0 * C2_ + ((jA ^ (m0 & 31)) << 3) + olow] = f2b(lrelu(fmaf(scA, acc00[rg], shA)));
        S2[m0 * C2_ + ((jB ^ (m0 & 31)) << 3) + olow] = f2b(lrelu(fmaf(scB, acc01[rg], shB)));
        S2[m1 * C2_ + ((jA ^ (m1 & 31)) << 3) + olow] = f2b(lrelu(fmaf(scA, acc10[rg], shA)));
        S2[m1 * C2_ + ((jB ^ (m1 & 31)) << 3) + olow] = f2b(lrelu(fmaf(scB, acc11[rg], shB)));
      }
    }
    __syncthreads();   // S2 half ready

    // ---- stage 3: X3 = S2 . W3^T ; stats + in-register pool over m
    {
      f32x16 acc00 = ZERO16, acc01 = ZERO16, acc10 = ZERO16, acc11 = ZERO16;
      int r0 = LB + l31, r1 = r0 + 32;
      const ushort* s2r0 = S2 + r0 * C2_;
      const ushort* s2r1 = S2 + r1 * C2_;
#pragma unroll
      for (int ks = 0; ks < 16; ++ks) {
        int j3 = ks * 2 + l5;
        s16x8 b0 = *(const s16x8*)(w3r0 + ks * 16);
        s16x8 b1 = *(const s16x8*)(w3r1 + ks * 16);
        s16x8 a0 = *(const s16x8*)(s2r0 + ((j3 ^ l31) << 3));
        s16x8 a1 = *(const s16x8*)(s2r1 + ((j3 ^ l31) << 3));
        acc00 = __builtin_amdgcn_mfma_f32_32x32x16_bf16(a0, b0, acc00, 0, 0, 0);
        acc01 = __builtin_amdgcn_mfma_f32_32x32x16_bf16(a0, b1, acc01, 0, 0, 0);
        acc10 = __builtin_amdgcn_mfma_f32_32x32x16_bf16(a1, b0, acc10, 0, 0, 0);
        acc11 = __builtin_amdgcn_mfma_f32_32x32x16_bf16(a1, b1, acc11, 0, 0, 0);
      }
      float pmx0 = -3.4e38f, pmn0 = 3.4e38f, pmx1 = -3.4e38f, pmn1 = 3.4e38f;
#pragma unroll
      for (int rg = 0; rg < 16; ++rg) {
        float v;
        v = acc00[rg]; pmx0 = fmaxf(pmx0, v); pmn0 = fminf(pmn0, v); sm0 += v; sq0 = fmaf(v, v, sq0);
        v = acc10[rg]; pmx0 = fmaxf(pmx0, v); pmn0 = fminf(pmn0, v); sm0 += v; sq0 = fmaf(v, v, sq0);
        v = acc01[rg]; pmx1 = fmaxf(pmx1, v); pmn1 = fminf(pmn1, v); sm1 += v; sq1 = fmaf(v, v, sq1);
        v = acc11[rg]; pmx1 = fmaxf(pmx1, v); pmn1 = fminf(pmn1, v); sm1 += v; sq1 = fmaf(v, v, sq1);
      }
      pmx0 = fmaxf(pmx0, __shfl_xor(pmx0, 32)); pmn0 = fminf(pmn0, __shfl_xor(pmn0, 32));
      pmx1 = fmaxf(pmx1, __shfl_xor(pmx1, 32)); pmn1 = fminf(pmn1, __shfl_xor(pmn1, 32));
      int nf = nf0 + RG * 2 + h;
      if (lane < 32) {
        Pmax[nf * C2_ + OB + l31] = pmx0;
        Pmin[nf * C2_ + OB + l31] = pmn0;
        Pmax[nf * C2_ + OB + 32 + l31] = pmx1;
        Pmin[nf * C2_ + OB + 32 + l31] = pmn1;
      }
    }
    __syncthreads();   // stage3 reads done before next half overwrites S2
  }
  sm0 += __shfl_xor(sm0, 32); sq0 += __shfl_xor(sq0, 32);
  sm1 += __shfl_xor(sm1, 32); sq1 += __shfl_xor(sq1, 32);
  if (lane < 32) {
    atomicAdd(&sum3[OB + l31], sm0);
    atomicAdd(&ssq3[OB + l31], sq0);
    atomicAdd(&sum3[OB + 32 + l31], sm1);
    atomicAdd(&ssq3[OB + 32 + l31], sq1);
  }
}

// ---------------- pool-select + fc1 (+stats4), inline bn3, 8 rows/block ----------------
__global__ __launch_bounds__(128) void k_fc1(const float* __restrict__ Pmax,
                                             const float* __restrict__ Pmin,
                                             const float* __restrict__ sum3,
                                             const float* __restrict__ ssq3,
                                             const float* __restrict__ g3v,
                                             const float* __restrict__ b3v,
                                             const float* __restrict__ w1,
                                             const float* __restrict__ b1v,
                                             float* __restrict__ X4,
                                             float* __restrict__ sum4,
                                             float* __restrict__ ssq4) {
  __shared__ float pooled[8][C2_];
  __shared__ float sc3s[C2_], sh3s[C2_];
  int row0 = blockIdx.x * 8, t = threadIdx.x;
  for (int o = t; o < C2_; o += 128) {   // inline bn3 params
    float mean = sum3[o] / CNT1;
    float var = ssq3[o] / CNT1 - mean * mean;
    float sc = g3v[o] * rsqrtf(var + EPSV);
    sc3s[o] = sc;
    sh3s[o] = b3v[o] - mean * sc;
  }
  __syncthreads();
  for (int idx = t; idx < 8 * C2_; idx += 128) {
    int r = idx >> 8, o = idx & 255;
    float sc = sc3s[o];
    float v = sc >= 0.f ? Pmax[(row0 + r) * C2_ + o] : Pmin[(row0 + r) * C2_ + o];
    pooled[r][o] = lrelu(fmaf(sc, v, sh3s[o]));
  }
  __syncthreads();
  const float* w = w1 + t * C2_;
  float bias = b1v[t];
  float acc[8] = {bias, bias, bias, bias, bias, bias, bias, bias};
  for (int c = 0; c < C2_; c += 4) {
    float4 wv = *(const float4*)(w + c);
#pragma unroll
    for (int r = 0; r < 8; ++r) {
      float4 pv = *(const float4*)(&pooled[r][c]);
      acc[r] = fmaf(wv.x, pv.x, fmaf(wv.y, pv.y, fmaf(wv.z, pv.z, fmaf(wv.w, pv.w, acc[r]))));
    }
  }
  float s = 0.f, s2 = 0.f;
#pragma unroll
  for (int r = 0; r < 8; ++r) {
    X4[(row0 + r) * H_ + t] = acc[r];
    s += acc[r]; s2 = fmaf(acc[r], acc[r], s2);
  }
  atomicAdd(&sum4[t], s);
  atomicAdd(&ssq4[t], s2);
}

// ---------------- bn4+relu + fc2 (+stats5), inline bn4, 8 rows/block ----------------
__global__ __launch_bounds__(64) void k_fc2(const float* __restrict__ X4,
                                            const float* __restrict__ sum4,
                                            const float* __restrict__ ssq4,
                                            const float* __restrict__ g4v,
                                            const float* __restrict__ b4v,
                                            const float* __restrict__ w2,
                                            const float* __restrict__ b2v,
                                            float* __restrict__ X5,
                                            float* __restrict__ sum5,
                                            float* __restrict__ ssq5) {
  __shared__ float y[8][H_];
  __shared__ float sc4s[H_], sh4s[H_];
  int row0 = blockIdx.x * 8, t = threadIdx.x;
  for (int j = t; j < H_; j += 64) {   // inline bn4 params
    float mean = sum4[j] / CNT45;
    float var = ssq4[j] / CNT45 - mean * mean;
    float sc = g4v[j] * rsqrtf(var + EPSV);
    sc4s[j] = sc;
    sh4s[j] = b4v[j] - mean * sc;
  }
  __syncthreads();
  for (int idx = t; idx < 8 * H_; idx += 64) {
    int r = idx >> 7, j = idx & 127;
    float x = fmaf(sc4s[j], X4[(row0 + r) * H_ + j], sh4s[j]);
    y[r][j] = x > 0.f ? x : 0.f;
  }
  __syncthreads();
  const float* w = w2 + t * H_;
  float bias = b2v[t];
  float acc[8] = {bias, bias, bias, bias, bias, bias, bias, bias};
  for (int c = 0; c < H_; c += 4) {
    float4 wv = *(const float4*)(w + c);
#pragma unroll
    for (int r = 0; r < 8; ++r) {
      float4 yv = *(const float4*)(&y[r][c]);
      acc[r] = fmaf(wv.x, yv.x, fmaf(wv.y, yv.y, fmaf(wv.z, yv.z, fmaf(wv.w, yv.w, acc[r]))));
    }
  }
  float s = 0.f, s2 = 0.f;
#pragma unroll
  for (int r = 0; r < 8; ++r) {
    X5[(row0 + r) * O_ + t] = acc[r];
    s += acc[r]; s2 = fmaf(acc[r], acc[r], s2);
  }
  atomicAdd(&sum5[t], s);
  atomicAdd(&ssq5[t], s2);
}

// ---------------- bn5 + relu -> out (inline bn5) ----------------
__global__ __launch_bounds__(256) void k_out(const float* __restrict__ X5,
                                             const float* __restrict__ sum5,
                                             const float* __restrict__ ssq5,
                                             const float* __restrict__ g5v,
                                             const float* __restrict__ b5v,
                                             float* __restrict__ out) {
  __shared__ float sc5s[O_], sh5s[O_];
  int t = threadIdx.x;
  if (t < O_) {
    float mean = sum5[t] / CNT45;
    float var = ssq5[t] / CNT45 - mean * mean;
    float sc = g5v[t] * rsqrtf(var + EPSV);
    sc5s[t] = sc;
    sh5s[t] = b5v[t] - mean * sc;
  }
  __syncthreads();
  int i = blockIdx.x * 256 + t;
  float x = fmaf(sc5s[i & (O_ - 1)], X5[i], sh5s[i & (O_ - 1)]);
  out[i] = x > 0.f ? x : 0.f;
}

// ---------------- launch ----------------
extern "C" void kernel_launch(void* const* d_in, const int* in_sizes, int n_in,
                              void* d_out, int out_size, void* d_ws, size_t ws_size,
                              hipStream_t stream) {
  const float* pf   = (const float*)d_in[0];
  const float* cf   = (const float*)d_in[1];
  const float* W1   = (const float*)d_in[2];
  const float* g1   = (const float*)d_in[3];
  const float* b1   = (const float*)d_in[4];
  const float* W2   = (const float*)d_in[5];
  const float* g2   = (const float*)d_in[6];
  const float* b2   = (const float*)d_in[7];
  const float* W3   = (const float*)d_in[8];
  const float* g3   = (const float*)d_in[9];
  const float* b3   = (const float*)d_in[10];
  const float* fc1w = (const float*)d_in[11];
  const float* fc1b = (const float*)d_in[12];
  const float* g4   = (const float*)d_in[13];
  const float* b4   = (const float*)d_in[14];
  const float* fc2w = (const float*)d_in[15];
  const float* fc2b = (const float*)d_in[16];
  const float* g5   = (const float*)d_in[17];
  const float* b5   = (const float*)d_in[18];
  float* ws  = (float*)d_ws;
  float* out = (float*)d_out;
  ushort* w2b = (ushort*)(ws + WS_W2BF);
  ushort* w3b = (ushort*)(ws + WS_W3BF);

  hipMemsetAsync(ws + WS_ZERO_BEG, 0, WS_ZERO_CNT * sizeof(float), stream);

  k_cvtW<<<(C2_ * C2_) / 256, 256, 0, stream>>>(W2, W3, w2b, w3b);
  k_proj4<<<B_ * N_ / 4, 128, 0, stream>>>(pf, W1, ws + WS_H1, 0);
  k_proj4<<<B_ * M_ / 4, 128, 0, stream>>>(cf, W1, ws + WS_HC, C_);
  k_rowstats<<<(B_ * N_) / 32, 256, 0, stream>>>(ws + WS_H1, ws + WS_SUMA, ws + WS_SSQA, N_);
  k_rowstats<<<(B_ * M_) / 32, 256, 0, stream>>>(ws + WS_HC, ws + WS_SUMC, ws + WS_SSQC, M_);
  k_x2f<<<B_ * N_ / 4, 512, 0, stream>>>(ws + WS_H1, ws + WS_HC,
                                         ws + WS_SUMA, ws + WS_SSQA, ws + WS_SUMC, ws + WS_SSQC,
                                         g1, b1, w2b, ws + WS_SUM2, ws + WS_SSQ2);
  k_x3f<<<B_ * N_ / 4, 512, 0, stream>>>(ws + WS_H1, ws + WS_HC,
                                         ws + WS_SUMA, ws + WS_SSQA, ws + WS_SUMC, ws + WS_SSQC,
                                         g1, b1, w2b,
                                         ws + WS_SUM2, ws + WS_SSQ2, g2, b2, w3b,
                                         ws + WS_SUM3, ws + WS_SSQ3,
                                         ws + WS_PMAX, ws + WS_PMIN);
  k_fc1<<<B_ * N_ / 8, 128, 0, stream>>>(ws + WS_PMAX, ws + WS_PMIN,
                                         ws + WS_SUM3, ws + WS_SSQ3, g3, b3,
                                         fc1w, fc1b, ws + WS_X4, ws + WS_SUM4, ws + WS_SSQ4);
  k_fc2<<<B_ * N_ / 8, 64, 0, stream>>>(ws + WS_X4, ws + WS_SUM4, ws + WS_SSQ4, g4, b4,
                                        fc2w, fc2b, ws + WS_X5, ws + WS_SUM5, ws + WS_SSQ5);
  k_out<<<(B_ * N_ * O_) / 256, 256, 0, stream>>>(ws + WS_X5, ws + WS_SUM5, ws + WS_SSQ5,
                                                  g5, b5, out);
}

// Round 11
// 350.308 us; speedup vs baseline: 1.3749x; 1.3749x over previous
//
#include <hip/hip_runtime.h>
#include <math.h>

#define EPSV   1e-5f
#define SLOPE  0.2f

#define B_   2
#define N_   2048
#define M_   64
#define C_   128
#define C2_  256
#define H_   128
#define O_   64

typedef short  s16x8  __attribute__((ext_vector_type(8)));
typedef ushort u16x8  __attribute__((ext_vector_type(8)));
typedef float  f32x16 __attribute__((ext_vector_type(16)));

#define ZERO16 {0.f,0.f,0.f,0.f,0.f,0.f,0.f,0.f,0.f,0.f,0.f,0.f,0.f,0.f,0.f,0.f}

// ---------------- workspace (float offsets) ----------------
#define WS_H1      0            // [4096*128]
#define WS_HC      524288       // [128*128]
#define WS_PMAX    540672       // [4096*256]
#define WS_PMIN    1589248      // [4096*256]
#define WS_W2BF    2637824      // 256*128 bf16
#define WS_W3BF    2654208      // 256*256 bf16
#define WS_SUMA    2686976      // [2*128]
#define WS_SSQA    2687232
#define WS_SUMC    2687488
#define WS_SSQC    2687744
#define WS_SUM2    2688000      // [256]
#define WS_SSQ2    2688256
#define WS_SUM3    2688512
#define WS_SSQ3    2688768
#define WS_SUM4    2689024      // [128]
#define WS_SSQ4    2689152
#define WS_SUM5    2689280      // [64]
#define WS_SSQ5    2689344
#define WS_ZERO_BEG WS_SUMA
#define WS_ZERO_CNT (2689408 - WS_SUMA)
#define WS_X4      WS_H1        // reuse (H1 dead after k_x3f)
#define WS_X5      WS_PMIN      // reuse (PMIN dead after k_fc1)

#define CNT1  ((float)B_ * N_ * M_)
#define CNT45 ((float)B_ * N_)

__device__ inline ushort f2b(float x) {
  unsigned u = __builtin_bit_cast(unsigned, x);
  u += 0x7fffu + ((u >> 16) & 1u);
  return (ushort)(u >> 16);
}
__device__ inline float lrelu(float x) { return fmaxf(x, SLOPE * x); }

// ---------------- W -> bf16 ----------------
__global__ __launch_bounds__(256) void k_cvtW(const float* __restrict__ W2,
                                              const float* __restrict__ W3,
                                              ushort* __restrict__ w2b,
                                              ushort* __restrict__ w3b) {
  int i = blockIdx.x * 256 + threadIdx.x;
  if (i < C2_ * C_) w2b[i] = f2b(W2[i]);
  w3b[i] = f2b(W3[i]);
}

// ---------------- projections, 4 rows/block ----------------
__global__ __launch_bounds__(128) void k_proj4(const float* __restrict__ x,
                                               const float* __restrict__ W1,
                                               float* __restrict__ out, int col_off) {
  __shared__ float xs[4][C_];
  int row0 = blockIdx.x * 4, t = threadIdx.x;
#pragma unroll
  for (int r = 0; r < 4; ++r) xs[r][t] = x[(row0 + r) * C_ + t];
  __syncthreads();
  const float* w = W1 + t * (2 * C_) + col_off;
  float acc[4] = {0.f, 0.f, 0.f, 0.f};
  for (int c = 0; c < C_; c += 4) {
    float4 wv = *(const float4*)(w + c);
#pragma unroll
    for (int r = 0; r < 4; ++r) {
      float4 xv = *(const float4*)(&xs[r][c]);
      acc[r] = fmaf(wv.x, xv.x, fmaf(wv.y, xv.y, fmaf(wv.z, xv.z, fmaf(wv.w, xv.w, acc[r]))));
    }
  }
#pragma unroll
  for (int r = 0; r < 4; ++r) out[(row0 + r) * C_ + t] = acc[r];
}

// ---------------- coalesced per-(b,c) row stats ----------------
__global__ __launch_bounds__(256) void k_rowstats(const float* __restrict__ x,
                                                  float* __restrict__ sums,
                                                  float* __restrict__ ssqs,
                                                  int rows_per_b) {
  __shared__ float red[256];
  int t = threadIdx.x, c = t & 127, rr = t >> 7;
  int r0 = blockIdx.x * 32, b = r0 / rows_per_b;
  float s = 0.f, s2 = 0.f;
  for (int i = 0; i < 16; ++i) {
    float v = x[(r0 + rr + i * 2) * C_ + c];
    s += v; s2 = fmaf(v, v, s2);
  }
  red[t] = s;
  __syncthreads();
  if (t < 128) atomicAdd(&sums[b * C_ + t], red[t] + red[t + 128]);
  __syncthreads();
  red[t] = s2;
  __syncthreads();
  if (t < 128) atomicAdd(&ssqs[b * C_ + t], red[t] + red[t + 128]);
}

// ---------------- build S1 tile: 128 rows (2 n x 64 m), inline bn1 ----------------
// S1 ushort idx: r*128 + ((j ^ (r&15))<<3) + (c&7),  j = c>>3
__device__ inline void build_S1_128(ushort* S1, const float* __restrict__ h1,
                                    const float* __restrict__ hc,
                                    const float* __restrict__ sumA,
                                    const float* __restrict__ ssqA,
                                    const float* __restrict__ sumC,
                                    const float* __restrict__ ssqC,
                                    const float* __restrict__ g1,
                                    const float* __restrict__ b1,
                                    int nf0, int b,
                                    float (*h1s)[C_], float* sc1, float* sh1) {
  int t = threadIdx.x;
  if (t < 256) h1s[t >> 7][t & 127] = h1[(nf0 + (t >> 7)) * C_ + (t & 127)];
  if (t < C_) {
    int c = t;
    float sA0 = sumA[c], sA1 = sumA[C_ + c], qA0 = ssqA[c], qA1 = ssqA[C_ + c];
    float sC0 = sumC[c], sC1 = sumC[C_ + c], qC0 = ssqC[c], qC1 = ssqC[C_ + c];
    float mean = ((float)M_ * (sA0 + sA1) + (float)N_ * (sC0 + sC1)) / CNT1;
    float ex2 = ((float)M_ * (qA0 + qA1) + (float)N_ * (qC0 + qC1)
                 + 2.f * (sA0 * sC0 + sA1 * sC1)) / CNT1;
    float var = ex2 - mean * mean;
    float sc = g1[c] * rsqrtf(var + EPSV);
    sc1[c] = sc;
    sh1[c] = b1[c] - mean * sc;
  }
  __syncthreads();
  const float* hcb = hc + b * M_ * C_;
#pragma unroll
  for (int i = 0; i < 4; ++i) {          // 128 rows * 16 slots / 512 thr
    int s = t + i * 512;
    int r = s >> 4, j = s & 15, c0 = j << 3;
    const float* hr = h1s[r >> 6];
    const float* src = hcb + (r & 63) * C_ + c0;
    float4 v0 = *(const float4*)(src);
    float4 v1 = *(const float4*)(src + 4);
    u16x8 q;
    q[0] = f2b(lrelu(fmaf(sc1[c0+0], hr[c0+0] + v0.x, sh1[c0+0])));
    q[1] = f2b(lrelu(fmaf(sc1[c0+1], hr[c0+1] + v0.y, sh1[c0+1])));
    q[2] = f2b(lrelu(fmaf(sc1[c0+2], hr[c0+2] + v0.z, sh1[c0+2])));
    q[3] = f2b(lrelu(fmaf(sc1[c0+3], hr[c0+3] + v0.w, sh1[c0+3])));
    q[4] = f2b(lrelu(fmaf(sc1[c0+4], hr[c0+4] + v1.x, sh1[c0+4])));
    q[5] = f2b(lrelu(fmaf(sc1[c0+5], hr[c0+5] + v1.y, sh1[c0+5])));
    q[6] = f2b(lrelu(fmaf(sc1[c0+6], hr[c0+6] + v1.z, sh1[c0+6])));
    q[7] = f2b(lrelu(fmaf(sc1[c0+7], hr[c0+7] + v1.w, sh1[c0+7])));
    *(u16x8*)(S1 + r * C_ + ((j ^ (r & 15)) << 3)) = q;
  }
  __syncthreads();
}

// ---------------- pass B: stats of X2 (128-row block, 8 col-groups, 2 accs) ----------------
__global__ __launch_bounds__(512, 4) void k_x2f(const float* __restrict__ h1,
                                                const float* __restrict__ hc,
                                                const float* __restrict__ sumA,
                                                const float* __restrict__ ssqA,
                                                const float* __restrict__ sumC,
                                                const float* __restrict__ ssqC,
                                                const float* __restrict__ g1v,
                                                const float* __restrict__ b1v,
                                                const ushort* __restrict__ W2b,
                                                float* __restrict__ sum2,
                                                float* __restrict__ ssq2) {
  __shared__ __align__(16) ushort S1[128 * C_];   // 32 KB
  __shared__ float h1s[2][C_], sc1[C_], sh1[C_];
  int nf0 = blockIdx.x * 2, b = nf0 >> 11;
  build_S1_128(S1, h1, hc, sumA, ssqA, sumC, ssqC, g1v, b1v, nf0, b, h1s, sc1, sh1);
  int t = threadIdx.x, wv = t >> 6, lane = t & 63, l31 = lane & 31, l5 = lane >> 5;
  int col = wv * 32 + l31;
  const ushort* wr = W2b + col * C_ + l5 * 8;
  float sm = 0.f, sq = 0.f;

#pragma unroll 1
  for (int h = 0; h < 2; ++h) {
    f32x16 acc0 = ZERO16, acc1 = ZERO16;
    int r0 = h * 64 + l31, r1 = r0 + 32;
    const ushort* s1r0 = S1 + r0 * C_;
    const ushort* s1r1 = S1 + r1 * C_;
    int rx0 = r0 & 15, rx1 = r1 & 15;
#pragma unroll
    for (int ks = 0; ks < 8; ++ks) {
      int j = ks * 2 + l5;
      s16x8 bv = *(const s16x8*)(wr + ks * 16);
      s16x8 a0 = *(const s16x8*)(s1r0 + ((j ^ rx0) << 3));
      s16x8 a1 = *(const s16x8*)(s1r1 + ((j ^ rx1) << 3));
      acc0 = __builtin_amdgcn_mfma_f32_32x32x16_bf16(a0, bv, acc0, 0, 0, 0);
      acc1 = __builtin_amdgcn_mfma_f32_32x32x16_bf16(a1, bv, acc1, 0, 0, 0);
    }
#pragma unroll
    for (int rg = 0; rg < 16; ++rg) {
      float v;
      v = acc0[rg]; sm += v; sq = fmaf(v, v, sq);
      v = acc1[rg]; sm += v; sq = fmaf(v, v, sq);
    }
  }
  sm += __shfl_xor(sm, 32); sq += __shfl_xor(sq, 32);
  if (lane < 32) {
    atomicAdd(&sum2[col], sm);
    atomicAdd(&ssq2[col], sq);
  }
}

// ---------------- pass C: stage2 + stage3 + pool (128-row block, 2 blocks/CU) ----------
// LDS: S1 32 KB + S2 32 KB (one 64-row half) + params ~3.5 KB -> ~68 KB.
// Wave = 8 col-groups x 32 cols; covers ALL 64 m-rows of the half -> in-wave pool.
// S2 ushort idx: r*256 + ((j3 ^ (r&31))<<3) + (o&7), j3 = o>>3
__global__ __launch_bounds__(512, 4) void k_x3f(const float* __restrict__ h1,
                                                const float* __restrict__ hc,
                                                const float* __restrict__ sumA,
                                                const float* __restrict__ ssqA,
                                                const float* __restrict__ sumC,
                                                const float* __restrict__ ssqC,
                                                const float* __restrict__ g1v,
                                                const float* __restrict__ b1v,
                                                const ushort* __restrict__ W2b,
                                                const float* __restrict__ sum2,
                                                const float* __restrict__ ssq2,
                                                const float* __restrict__ g2v,
                                                const float* __restrict__ b2v,
                                                const ushort* __restrict__ W3b,
                                                float* __restrict__ sum3,
                                                float* __restrict__ ssq3,
                                                float* __restrict__ Pmax,
                                                float* __restrict__ Pmin) {
  __shared__ __align__(16) ushort S1[128 * C_];    // 32 KB
  __shared__ __align__(16) ushort S2[64 * C2_];    // 32 KB (one 64-row half)
  __shared__ float h1s[2][C_], sc1[C_], sh1[C_];
  __shared__ float sc2s[C2_], sh2s[C2_];
  int nf0 = blockIdx.x * 2, b = nf0 >> 11;
  int t = threadIdx.x;
  if (t < C2_) {   // inline bn2 params
    float mean = sum2[t] / CNT1;
    float var = ssq2[t] / CNT1 - mean * mean;
    float sc = g2v[t] * rsqrtf(var + EPSV);
    sc2s[t] = sc;
    sh2s[t] = b2v[t] - mean * sc;
  }
  build_S1_128(S1, h1, hc, sumA, ssqA, sumC, ssqC, g1v, b1v, nf0, b, h1s, sc1, sh1);
  int wv = t >> 6, lane = t & 63, l31 = lane & 31, l5 = lane >> 5;
  int col = wv * 32 + l31;
  const ushort* w2r = W2b + col * C_ + l5 * 8;
  const ushort* w3r = W3b + col * C2_ + l5 * 8;
  int jc = col >> 3, olow = col & 7;
  float sc2 = sc2s[col], sh2 = sh2s[col];
  float sm = 0.f, sq = 0.f;

#pragma unroll 1
  for (int h = 0; h < 2; ++h) {
    // ---- stage 2: this half's 64 rows x wave's 32 cols -> S2
    {
      f32x16 acc0 = ZERO16, acc1 = ZERO16;
      int r0 = h * 64 + l31, r1 = r0 + 32;
      const ushort* s1r0 = S1 + r0 * C_;
      const ushort* s1r1 = S1 + r1 * C_;
      int rx0 = r0 & 15, rx1 = r1 & 15;
#pragma unroll
      for (int ks = 0; ks < 8; ++ks) {
        int j = ks * 2 + l5;
        s16x8 bv = *(const s16x8*)(w2r + ks * 16);
        s16x8 a0 = *(const s16x8*)(s1r0 + ((j ^ rx0) << 3));
        s16x8 a1 = *(const s16x8*)(s1r1 + ((j ^ rx1) << 3));
        acc0 = __builtin_amdgcn_mfma_f32_32x32x16_bf16(a0, bv, acc0, 0, 0, 0);
        acc1 = __builtin_amdgcn_mfma_f32_32x32x16_bf16(a1, bv, acc1, 0, 0, 0);
      }
#pragma unroll
      for (int rg = 0; rg < 16; ++rg) {
        int rp = (rg & 3) + 8 * (rg >> 2) + 4 * l5;   // 0..31
        int m0 = rp, m1 = rp + 32;                    // S2 local rows
        S2[m0 * C2_ + ((jc ^ (m0 & 31)) << 3) + olow] = f2b(lrelu(fmaf(sc2, acc0[rg], sh2)));
        S2[m1 * C2_ + ((jc ^ (m1 & 31)) << 3) + olow] = f2b(lrelu(fmaf(sc2, acc1[rg], sh2)));
      }
    }
    __syncthreads();   // S2 half ready

    // ---- stage 3: X3 = S2 . W3^T over all 64 rows; in-wave pool over m
    {
      f32x16 acc0 = ZERO16, acc1 = ZERO16;
      const ushort* s2r0 = S2 + l31 * C2_;
      const ushort* s2r1 = S2 + (l31 + 32) * C2_;
#pragma unroll
      for (int ks = 0; ks < 16; ++ks) {
        int j3 = ks * 2 + l5;
        s16x8 bv = *(const s16x8*)(w3r + ks * 16);
        s16x8 a0 = *(const s16x8*)(s2r0 + ((j3 ^ l31) << 3));
        s16x8 a1 = *(const s16x8*)(s2r1 + ((j3 ^ l31) << 3));
        acc0 = __builtin_amdgcn_mfma_f32_32x32x16_bf16(a0, bv, acc0, 0, 0, 0);
        acc1 = __builtin_amdgcn_mfma_f32_32x32x16_bf16(a1, bv, acc1, 0, 0, 0);
      }
      float pmx = -3.4e38f, pmn = 3.4e38f;
#pragma unroll
      for (int rg = 0; rg < 16; ++rg) {
        float v;
        v = acc0[rg]; pmx = fmaxf(pmx, v); pmn = fminf(pmn, v); sm += v; sq = fmaf(v, v, sq);
        v = acc1[rg]; pmx = fmaxf(pmx, v); pmn = fminf(pmn, v); sm += v; sq = fmaf(v, v, sq);
      }
      pmx = fmaxf(pmx, __shfl_xor(pmx, 32));
      pmn = fminf(pmn, __shfl_xor(pmn, 32));
      int nf = nf0 + h;
      if (lane < 32) {
        Pmax[nf * C2_ + col] = pmx;
        Pmin[nf * C2_ + col] = pmn;
      }
    }
    __syncthreads();   // stage3 reads done before next half overwrites S2
  }
  sm += __shfl_xor(sm, 32); sq += __shfl_xor(sq, 32);
  if (lane < 32) {
    atomicAdd(&sum3[col], sm);
    atomicAdd(&ssq3[col], sq);
  }
}

// ---------------- pool-select + fc1 (+stats4), inline bn3, 8 rows/block ----------------
__global__ __launch_bounds__(128) void k_fc1(const float* __restrict__ Pmax,
                                             const float* __restrict__ Pmin,
                                             const float* __restrict__ sum3,
                                             const float* __restrict__ ssq3,
                                             const float* __restrict__ g3v,
                                             const float* __restrict__ b3v,
                                             const float* __restrict__ w1,
                                             const float* __restrict__ b1v,
                                             float* __restrict__ X4,
                                             float* __restrict__ sum4,
                                             float* __restrict__ ssq4) {
  __shared__ float pooled[8][C2_];
  __shared__ float sc3s[C2_], sh3s[C2_];
  int row0 = blockIdx.x * 8, t = threadIdx.x;
  for (int o = t; o < C2_; o += 128) {
    float mean = sum3[o] / CNT1;
    float var = ssq3[o] / CNT1 - mean * mean;
    float sc = g3v[o] * rsqrtf(var + EPSV);
    sc3s[o] = sc;
    sh3s[o] = b3v[o] - mean * sc;
  }
  __syncthreads();
  for (int idx = t; idx < 8 * C2_; idx += 128) {
    int r = idx >> 8, o = idx & 255;
    float sc = sc3s[o];
    float v = sc >= 0.f ? Pmax[(row0 + r) * C2_ + o] : Pmin[(row0 + r) * C2_ + o];
    pooled[r][o] = lrelu(fmaf(sc, v, sh3s[o]));
  }
  __syncthreads();
  const float* w = w1 + t * C2_;
  float bias = b1v[t];
  float acc[8] = {bias, bias, bias, bias, bias, bias, bias, bias};
  for (int c = 0; c < C2_; c += 4) {
    float4 wv = *(const float4*)(w + c);
#pragma unroll
    for (int r = 0; r < 8; ++r) {
      float4 pv = *(const float4*)(&pooled[r][c]);
      acc[r] = fmaf(wv.x, pv.x, fmaf(wv.y, pv.y, fmaf(wv.z, pv.z, fmaf(wv.w, pv.w, acc[r]))));
    }
  }
  float s = 0.f, s2 = 0.f;
#pragma unroll
  for (int r = 0; r < 8; ++r) {
    X4[(row0 + r) * H_ + t] = acc[r];
    s += acc[r]; s2 = fmaf(acc[r], acc[r], s2);
  }
  atomicAdd(&sum4[t], s);
  atomicAdd(&ssq4[t], s2);
}

// ---------------- bn4+relu + fc2 (+stats5), inline bn4, 8 rows/block ----------------
__global__ __launch_bounds__(64) void k_fc2(const float* __restrict__ X4,
                                            const float* __restrict__ sum4,
                                            const float* __restrict__ ssq4,
                                            const float* __restrict__ g4v,
                                            const float* __restrict__ b4v,
                                            const float* __restrict__ w2,
                                            const float* __restrict__ b2v,
                                            float* __restrict__ X5,
                                            float* __restrict__ sum5,
                                            float* __restrict__ ssq5) {
  __shared__ float y[8][H_];
  __shared__ float sc4s[H_], sh4s[H_];
  int row0 = blockIdx.x * 8, t = threadIdx.x;
  for (int j = t; j < H_; j += 64) {
    float mean = sum4[j] / CNT45;
    float var = ssq4[j] / CNT45 - mean * mean;
    float sc = g4v[j] * rsqrtf(var + EPSV);
    sc4s[j] = sc;
    sh4s[j] = b4v[j] - mean * sc;
  }
  __syncthreads();
  for (int idx = t; idx < 8 * H_; idx += 64) {
    int r = idx >> 7, j = idx & 127;
    float x = fmaf(sc4s[j], X4[(row0 + r) * H_ + j], sh4s[j]);
    y[r][j] = x > 0.f ? x : 0.f;
  }
  __syncthreads();
  const float* w = w2 + t * H_;
  float bias = b2v[t];
  float acc[8] = {bias, bias, bias, bias, bias, bias, bias, bias};
  for (int c = 0; c < H_; c += 4) {
    float4 wv = *(const float4*)(w + c);
#pragma unroll
    for (int r = 0; r < 8; ++r) {
      float4 yv = *(const float4*)(&y[r][c]);
      acc[r] = fmaf(wv.x, yv.x, fmaf(wv.y, yv.y, fmaf(wv.z, yv.z, fmaf(wv.w, yv.w, acc[r]))));
    }
  }
  float s = 0.f, s2 = 0.f;
#pragma unroll
  for (int r = 0; r < 8; ++r) {
    X5[(row0 + r) * O_ + t] = acc[r];
    s += acc[r]; s2 = fmaf(acc[r], acc[r], s2);
  }
  atomicAdd(&sum5[t], s);
  atomicAdd(&ssq5[t], s2);
}

// ---------------- bn5 + relu -> out (inline bn5) ----------------
__global__ __launch_bounds__(256) void k_out(const float* __restrict__ X5,
                                             const float* __restrict__ sum5,
                                             const float* __restrict__ ssq5,
                                             const float* __restrict__ g5v,
                                             const float* __restrict__ b5v,
                                             float* __restrict__ out) {
  __shared__ float sc5s[O_], sh5s[O_];
  int t = threadIdx.x;
  if (t < O_) {
    float mean = sum5[t] / CNT45;
    float var = ssq5[t] / CNT45 - mean * mean;
    float sc = g5v[t] * rsqrtf(var + EPSV);
    sc5s[t] = sc;
    sh5s[t] = b5v[t] - mean * sc;
  }
  __syncthreads();
  int i = blockIdx.x * 256 + t;
  float x = fmaf(sc5s[i & (O_ - 1)], X5[i], sh5s[i & (O_ - 1)]);
  out[i] = x > 0.f ? x : 0.f;
}

// ---------------- launch ----------------
extern "C" void kernel_launch(void* const* d_in, const int* in_sizes, int n_in,
                              void* d_out, int out_size, void* d_ws, size_t ws_size,
                              hipStream_t stream) {
  const float* pf   = (const float*)d_in[0];
  const float* cf   = (const float*)d_in[1];
  const float* W1   = (const float*)d_in[2];
  const float* g1   = (const float*)d_in[3];
  const float* b1   = (const float*)d_in[4];
  const float* W2   = (const float*)d_in[5];
  const float* g2   = (const float*)d_in[6];
  const float* b2   = (const float*)d_in[7];
  const float* W3   = (const float*)d_in[8];
  const float* g3   = (const float*)d_in[9];
  const float* b3   = (const float*)d_in[10];
  const float* fc1w = (const float*)d_in[11];
  const float* fc1b = (const float*)d_in[12];
  const float* g4   = (const float*)d_in[13];
  const float* b4   = (const float*)d_in[14];
  const float* fc2w = (const float*)d_in[15];
  const float* fc2b = (const float*)d_in[16];
  const float* g5   = (const float*)d_in[17];
  const float* b5   = (const float*)d_in[18];
  float* ws  = (float*)d_ws;
  float* out = (float*)d_out;
  ushort* w2b = (ushort*)(ws + WS_W2BF);
  ushort* w3b = (ushort*)(ws + WS_W3BF);

  hipMemsetAsync(ws + WS_ZERO_BEG, 0, WS_ZERO_CNT * sizeof(float), stream);

  k_cvtW<<<(C2_ * C2_) / 256, 256, 0, stream>>>(W2, W3, w2b, w3b);
  k_proj4<<<B_ * N_ / 4, 128, 0, stream>>>(pf, W1, ws + WS_H1, 0);
  k_proj4<<<B_ * M_ / 4, 128, 0, stream>>>(cf, W1, ws + WS_HC, C_);
  k_rowstats<<<(B_ * N_) / 32, 256, 0, stream>>>(ws + WS_H1, ws + WS_SUMA, ws + WS_SSQA, N_);
  k_rowstats<<<(B_ * M_) / 32, 256, 0, stream>>>(ws + WS_HC, ws + WS_SUMC, ws + WS_SSQC, M_);
  k_x2f<<<B_ * N_ / 2, 512, 0, stream>>>(ws + WS_H1, ws + WS_HC,
                                         ws + WS_SUMA, ws + WS_SSQA, ws + WS_SUMC, ws + WS_SSQC,
                                         g1, b1, w2b, ws + WS_SUM2, ws + WS_SSQ2);
  k_x3f<<<B_ * N_ / 2, 512, 0, stream>>>(ws + WS_H1, ws + WS_HC,
                                         ws + WS_SUMA, ws + WS_SSQA, ws + WS_SUMC, ws + WS_SSQC,
                                         g1, b1, w2b,
                                         ws + WS_SUM2, ws + WS_SSQ2, g2, b2, w3b,
                                         ws + WS_SUM3, ws + WS_SSQ3,
                                         ws + WS_PMAX, ws + WS_PMIN);
  k_fc1<<<B_ * N_ / 8, 128, 0, stream>>>(ws + WS_PMAX, ws + WS_PMIN,
                                         ws + WS_SUM3, ws + WS_SSQ3, g3, b3,
                                         fc1w, fc1b, ws + WS_X4, ws + WS_SUM4, ws + WS_SSQ4);
  k_fc2<<<B_ * N_ / 8, 64, 0, stream>>>(ws + WS_X4, ws + WS_SUM4, ws + WS_SSQ4, g4, b4,
                                        fc2w, fc2b, ws + WS_X5, ws + WS_SUM5, ws + WS_SSQ5);
  k_out<<<(B_ * N_ * O_) / 256, 256, 0, stream>>>(ws + WS_X5, ws + WS_SUM5, ws + WS_SSQ5,
                                                  g5, b5, out);
}

// Round 12
// 242.757 us; speedup vs baseline: 1.9840x; 1.4430x over previous
//
#include <hip/hip_runtime.h>
#include <math.h>

#define EPSV   1e-5f
#define SLOPE  0.2f

#define B_   2
#define N_   2048
#define M_   64
#define C_   128
#define C2_  256
#define H_   128
#define O_   64

typedef short  s16x8  __attribute__((ext_vector_type(8)));
typedef ushort u16x8  __attribute__((ext_vector_type(8)));
typedef float  f32x16 __attribute__((ext_vector_type(16)));

#define ZERO16 {0.f,0.f,0.f,0.f,0.f,0.f,0.f,0.f,0.f,0.f,0.f,0.f,0.f,0.f,0.f,0.f}

// ---------------- workspace (float offsets) ----------------
#define WS_H1      0            // [4096*128]
#define WS_HC      524288       // [128*128]
#define WS_PMAX    540672       // [4096*256]
#define WS_PMIN    1589248      // [4096*256]
#define WS_W2BF    2637824      // 256*128 bf16
#define WS_W3BF    2654208      // 256*256 bf16
#define WS_SUMA    2686976      // [2*128]
#define WS_SSQA    2687232
#define WS_SUMC    2687488
#define WS_SSQC    2687744
#define WS_SUM2    2688000      // [256]
#define WS_SSQ2    2688256
#define WS_SUM3    2688512
#define WS_SSQ3    2688768
#define WS_SUM4    2689024      // [128]
#define WS_SSQ4    2689152
#define WS_SUM5    2689280      // [64]
#define WS_SSQ5    2689344
#define WS_ZERO_BEG WS_SUMA
#define WS_ZERO_CNT (2689408 - WS_SUMA)
#define WS_X4      WS_H1        // reuse (H1 dead after k_x3f)
#define WS_X5      WS_PMIN      // reuse (PMIN dead after k_fc1)

#define CNT1  ((float)B_ * N_ * M_)
#define CNT45 ((float)B_ * N_)

__device__ inline ushort f2b(float x) {
  unsigned u = __builtin_bit_cast(unsigned, x);
  u += 0x7fffu + ((u >> 16) & 1u);
  return (ushort)(u >> 16);
}
__device__ inline float lrelu(float x) { return fmaxf(x, SLOPE * x); }

// ---------------- W -> bf16 ----------------
__global__ __launch_bounds__(256) void k_cvtW(const float* __restrict__ W2,
                                              const float* __restrict__ W3,
                                              ushort* __restrict__ w2b,
                                              ushort* __restrict__ w3b) {
  int i = blockIdx.x * 256 + threadIdx.x;
  if (i < C2_ * C_) w2b[i] = f2b(W2[i]);
  w3b[i] = f2b(W3[i]);
}

// ---------------- projections, 4 rows/block ----------------
__global__ __launch_bounds__(128) void k_proj4(const float* __restrict__ x,
                                               const float* __restrict__ W1,
                                               float* __restrict__ out, int col_off) {
  __shared__ float xs[4][C_];
  int row0 = blockIdx.x * 4, t = threadIdx.x;
#pragma unroll
  for (int r = 0; r < 4; ++r) xs[r][t] = x[(row0 + r) * C_ + t];
  __syncthreads();
  const float* w = W1 + t * (2 * C_) + col_off;
  float acc[4] = {0.f, 0.f, 0.f, 0.f};
  for (int c = 0; c < C_; c += 4) {
    float4 wv = *(const float4*)(w + c);
#pragma unroll
    for (int r = 0; r < 4; ++r) {
      float4 xv = *(const float4*)(&xs[r][c]);
      acc[r] = fmaf(wv.x, xv.x, fmaf(wv.y, xv.y, fmaf(wv.z, xv.z, fmaf(wv.w, xv.w, acc[r]))));
    }
  }
#pragma unroll
  for (int r = 0; r < 4; ++r) out[(row0 + r) * C_ + t] = acc[r];
}

// ---------------- coalesced per-(b,c) row stats ----------------
__global__ __launch_bounds__(256) void k_rowstats(const float* __restrict__ x,
                                                  float* __restrict__ sums,
                                                  float* __restrict__ ssqs,
                                                  int rows_per_b) {
  __shared__ float red[256];
  int t = threadIdx.x, c = t & 127, rr = t >> 7;
  int r0 = blockIdx.x * 32, b = r0 / rows_per_b;
  float s = 0.f, s2 = 0.f;
  for (int i = 0; i < 16; ++i) {
    float v = x[(r0 + rr + i * 2) * C_ + c];
    s += v; s2 = fmaf(v, v, s2);
  }
  red[t] = s;
  __syncthreads();
  if (t < 128) atomicAdd(&sums[b * C_ + t], red[t] + red[t + 128]);
  __syncthreads();
  red[t] = s2;
  __syncthreads();
  if (t < 128) atomicAdd(&ssqs[b * C_ + t], red[t] + red[t + 128]);
}

// ---------------- build S1 tile: 128 rows (2 n x 64 m), inline bn1 ----------------
// S1 ushort idx: r*128 + ((j ^ (r&15))<<3) + (c&7),  j = c>>3
__device__ inline void build_S1_128(ushort* S1, const float* __restrict__ h1,
                                    const float* __restrict__ hc,
                                    const float* __restrict__ sumA,
                                    const float* __restrict__ ssqA,
                                    const float* __restrict__ sumC,
                                    const float* __restrict__ ssqC,
                                    const float* __restrict__ g1,
                                    const float* __restrict__ b1,
                                    int nf0, int b,
                                    float (*h1s)[C_], float* sc1, float* sh1) {
  int t = threadIdx.x;
  if (t < 256) h1s[t >> 7][t & 127] = h1[(nf0 + (t >> 7)) * C_ + (t & 127)];
  if (t < C_) {
    int c = t;
    float sA0 = sumA[c], sA1 = sumA[C_ + c], qA0 = ssqA[c], qA1 = ssqA[C_ + c];
    float sC0 = sumC[c], sC1 = sumC[C_ + c], qC0 = ssqC[c], qC1 = ssqC[C_ + c];
    float mean = ((float)M_ * (sA0 + sA1) + (float)N_ * (sC0 + sC1)) / CNT1;
    float ex2 = ((float)M_ * (qA0 + qA1) + (float)N_ * (qC0 + qC1)
                 + 2.f * (sA0 * sC0 + sA1 * sC1)) / CNT1;
    float var = ex2 - mean * mean;
    float sc = g1[c] * rsqrtf(var + EPSV);
    sc1[c] = sc;
    sh1[c] = b1[c] - mean * sc;
  }
  __syncthreads();
  const float* hcb = hc + b * M_ * C_;
#pragma unroll
  for (int i = 0; i < 4; ++i) {          // 128 rows * 16 slots / 512 thr
    int s = t + i * 512;
    int r = s >> 4, j = s & 15, c0 = j << 3;
    const float* hr = h1s[r >> 6];
    const float* src = hcb + (r & 63) * C_ + c0;
    float4 v0 = *(const float4*)(src);
    float4 v1 = *(const float4*)(src + 4);
    u16x8 q;
    q[0] = f2b(lrelu(fmaf(sc1[c0+0], hr[c0+0] + v0.x, sh1[c0+0])));
    q[1] = f2b(lrelu(fmaf(sc1[c0+1], hr[c0+1] + v0.y, sh1[c0+1])));
    q[2] = f2b(lrelu(fmaf(sc1[c0+2], hr[c0+2] + v0.z, sh1[c0+2])));
    q[3] = f2b(lrelu(fmaf(sc1[c0+3], hr[c0+3] + v0.w, sh1[c0+3])));
    q[4] = f2b(lrelu(fmaf(sc1[c0+4], hr[c0+4] + v1.x, sh1[c0+4])));
    q[5] = f2b(lrelu(fmaf(sc1[c0+5], hr[c0+5] + v1.y, sh1[c0+5])));
    q[6] = f2b(lrelu(fmaf(sc1[c0+6], hr[c0+6] + v1.z, sh1[c0+6])));
    q[7] = f2b(lrelu(fmaf(sc1[c0+7], hr[c0+7] + v1.w, sh1[c0+7])));
    *(u16x8*)(S1 + r * C_ + ((j ^ (r & 15)) << 3)) = q;
  }
  __syncthreads();
}

// ---------------- pass B: stats of X2 (128-row block, 8 col-groups, 2 accs) ----------------
// (512,2): VGPR cap 128 — proven no-spill for this ~70-live structure (R7/R9).
__global__ __launch_bounds__(512, 2) void k_x2f(const float* __restrict__ h1,
                                                const float* __restrict__ hc,
                                                const float* __restrict__ sumA,
                                                const float* __restrict__ ssqA,
                                                const float* __restrict__ sumC,
                                                const float* __restrict__ ssqC,
                                                const float* __restrict__ g1v,
                                                const float* __restrict__ b1v,
                                                const ushort* __restrict__ W2b,
                                                float* __restrict__ sum2,
                                                float* __restrict__ ssq2) {
  __shared__ __align__(16) ushort S1[128 * C_];   // 32 KB
  __shared__ float h1s[2][C_], sc1[C_], sh1[C_];
  int nf0 = blockIdx.x * 2, b = nf0 >> 11;
  build_S1_128(S1, h1, hc, sumA, ssqA, sumC, ssqC, g1v, b1v, nf0, b, h1s, sc1, sh1);
  int t = threadIdx.x, wv = t >> 6, lane = t & 63, l31 = lane & 31, l5 = lane >> 5;
  int col = wv * 32 + l31;
  const ushort* wr = W2b + col * C_ + l5 * 8;
  float sm = 0.f, sq = 0.f;

#pragma unroll 1
  for (int h = 0; h < 2; ++h) {
    f32x16 acc0 = ZERO16, acc1 = ZERO16;
    int r0 = h * 64 + l31, r1 = r0 + 32;
    const ushort* s1r0 = S1 + r0 * C_;
    const ushort* s1r1 = S1 + r1 * C_;
    int rx0 = r0 & 15, rx1 = r1 & 15;
#pragma unroll
    for (int ks = 0; ks < 8; ++ks) {
      int j = ks * 2 + l5;
      s16x8 bv = *(const s16x8*)(wr + ks * 16);
      s16x8 a0 = *(const s16x8*)(s1r0 + ((j ^ rx0) << 3));
      s16x8 a1 = *(const s16x8*)(s1r1 + ((j ^ rx1) << 3));
      acc0 = __builtin_amdgcn_mfma_f32_32x32x16_bf16(a0, bv, acc0, 0, 0, 0);
      acc1 = __builtin_amdgcn_mfma_f32_32x32x16_bf16(a1, bv, acc1, 0, 0, 0);
    }
#pragma unroll
    for (int rg = 0; rg < 16; ++rg) {
      float v;
      v = acc0[rg]; sm += v; sq = fmaf(v, v, sq);
      v = acc1[rg]; sm += v; sq = fmaf(v, v, sq);
    }
  }
  sm += __shfl_xor(sm, 32); sq += __shfl_xor(sq, 32);
  if (lane < 32) {
    atomicAdd(&sum2[col], sm);
    atomicAdd(&ssq2[col], sq);
  }
}

// ---------------- pass C: stage2 + stage3 + pool (128-row block, 2 blocks/CU) ----------
// LDS: S1 32 KB + S2 32 KB + params ~3.5 KB -> ~68 KB -> 2 blocks/CU.
// (512,2): VGPR cap 128, ~75 live -> no spill (R11's (512,4) capped at 64 and spilled).
// S2 ushort idx: r*256 + ((j3 ^ (r&31))<<3) + (o&7), j3 = o>>3
__global__ __launch_bounds__(512, 2) void k_x3f(const float* __restrict__ h1,
                                                const float* __restrict__ hc,
                                                const float* __restrict__ sumA,
                                                const float* __restrict__ ssqA,
                                                const float* __restrict__ sumC,
                                                const float* __restrict__ ssqC,
                                                const float* __restrict__ g1v,
                                                const float* __restrict__ b1v,
                                                const ushort* __restrict__ W2b,
                                                const float* __restrict__ sum2,
                                                const float* __restrict__ ssq2,
                                                const float* __restrict__ g2v,
                                                const float* __restrict__ b2v,
                                                const ushort* __restrict__ W3b,
                                                float* __restrict__ sum3,
                                                float* __restrict__ ssq3,
                                                float* __restrict__ Pmax,
                                                float* __restrict__ Pmin) {
  __shared__ __align__(16) ushort S1[128 * C_];    // 32 KB
  __shared__ __align__(16) ushort S2[64 * C2_];    // 32 KB (one 64-row half)
  __shared__ float h1s[2][C_], sc1[C_], sh1[C_];
  __shared__ float sc2s[C2_], sh2s[C2_];
  int nf0 = blockIdx.x * 2, b = nf0 >> 11;
  int t = threadIdx.x;
  if (t < C2_) {   // inline bn2 params
    float mean = sum2[t] / CNT1;
    float var = ssq2[t] / CNT1 - mean * mean;
    float sc = g2v[t] * rsqrtf(var + EPSV);
    sc2s[t] = sc;
    sh2s[t] = b2v[t] - mean * sc;
  }
  build_S1_128(S1, h1, hc, sumA, ssqA, sumC, ssqC, g1v, b1v, nf0, b, h1s, sc1, sh1);
  int wv = t >> 6, lane = t & 63, l31 = lane & 31, l5 = lane >> 5;
  int col = wv * 32 + l31;
  const ushort* w2r = W2b + col * C_ + l5 * 8;
  const ushort* w3r = W3b + col * C2_ + l5 * 8;
  int jc = col >> 3, olow = col & 7;
  float sc2 = sc2s[col], sh2 = sh2s[col];
  float sm = 0.f, sq = 0.f;

#pragma unroll 1
  for (int h = 0; h < 2; ++h) {
    // ---- stage 2: this half's 64 rows x wave's 32 cols -> S2
    {
      f32x16 acc0 = ZERO16, acc1 = ZERO16;
      int r0 = h * 64 + l31, r1 = r0 + 32;
      const ushort* s1r0 = S1 + r0 * C_;
      const ushort* s1r1 = S1 + r1 * C_;
      int rx0 = r0 & 15, rx1 = r1 & 15;
#pragma unroll
      for (int ks = 0; ks < 8; ++ks) {
        int j = ks * 2 + l5;
        s16x8 bv = *(const s16x8*)(w2r + ks * 16);
        s16x8 a0 = *(const s16x8*)(s1r0 + ((j ^ rx0) << 3));
        s16x8 a1 = *(const s16x8*)(s1r1 + ((j ^ rx1) << 3));
        acc0 = __builtin_amdgcn_mfma_f32_32x32x16_bf16(a0, bv, acc0, 0, 0, 0);
        acc1 = __builtin_amdgcn_mfma_f32_32x32x16_bf16(a1, bv, acc1, 0, 0, 0);
      }
#pragma unroll
      for (int rg = 0; rg < 16; ++rg) {
        int rp = (rg & 3) + 8 * (rg >> 2) + 4 * l5;   // 0..31
        int m0 = rp, m1 = rp + 32;                    // S2 local rows
        S2[m0 * C2_ + ((jc ^ (m0 & 31)) << 3) + olow] = f2b(lrelu(fmaf(sc2, acc0[rg], sh2)));
        S2[m1 * C2_ + ((jc ^ (m1 & 31)) << 3) + olow] = f2b(lrelu(fmaf(sc2, acc1[rg], sh2)));
      }
    }
    __syncthreads();   // S2 half ready

    // ---- stage 3: X3 = S2 . W3^T over all 64 rows; in-wave pool over m
    {
      f32x16 acc0 = ZERO16, acc1 = ZERO16;
      const ushort* s2r0 = S2 + l31 * C2_;
      const ushort* s2r1 = S2 + (l31 + 32) * C2_;
#pragma unroll
      for (int ks = 0; ks < 16; ++ks) {
        int j3 = ks * 2 + l5;
        s16x8 bv = *(const s16x8*)(w3r + ks * 16);
        s16x8 a0 = *(const s16x8*)(s2r0 + ((j3 ^ l31) << 3));
        s16x8 a1 = *(const s16x8*)(s2r1 + ((j3 ^ l31) << 3));
        acc0 = __builtin_amdgcn_mfma_f32_32x32x16_bf16(a0, bv, acc0, 0, 0, 0);
        acc1 = __builtin_amdgcn_mfma_f32_32x32x16_bf16(a1, bv, acc1, 0, 0, 0);
      }
      float pmx = -3.4e38f, pmn = 3.4e38f;
#pragma unroll
      for (int rg = 0; rg < 16; ++rg) {
        float v;
        v = acc0[rg]; pmx = fmaxf(pmx, v); pmn = fminf(pmn, v); sm += v; sq = fmaf(v, v, sq);
        v = acc1[rg]; pmx = fmaxf(pmx, v); pmn = fminf(pmn, v); sm += v; sq = fmaf(v, v, sq);
      }
      pmx = fmaxf(pmx, __shfl_xor(pmx, 32));
      pmn = fminf(pmn, __shfl_xor(pmn, 32));
      int nf = nf0 + h;
      if (lane < 32) {
        Pmax[nf * C2_ + col] = pmx;
        Pmin[nf * C2_ + col] = pmn;
      }
    }
    __syncthreads();   // stage3 reads done before next half overwrites S2
  }
  sm += __shfl_xor(sm, 32); sq += __shfl_xor(sq, 32);
  if (lane < 32) {
    atomicAdd(&sum3[col], sm);
    atomicAdd(&ssq3[col], sq);
  }
}

// ---------------- pool-select + fc1 (+stats4), inline bn3, 8 rows/block ----------------
__global__ __launch_bounds__(128) void k_fc1(const float* __restrict__ Pmax,
                                             const float* __restrict__ Pmin,
                                             const float* __restrict__ sum3,
                                             const float* __restrict__ ssq3,
                                             const float* __restrict__ g3v,
                                             const float* __restrict__ b3v,
                                             const float* __restrict__ w1,
                                             const float* __restrict__ b1v,
                                             float* __restrict__ X4,
                                             float* __restrict__ sum4,
                                             float* __restrict__ ssq4) {
  __shared__ float pooled[8][C2_];
  __shared__ float sc3s[C2_], sh3s[C2_];
  int row0 = blockIdx.x * 8, t = threadIdx.x;
  for (int o = t; o < C2_; o += 128) {
    float mean = sum3[o] / CNT1;
    float var = ssq3[o] / CNT1 - mean * mean;
    float sc = g3v[o] * rsqrtf(var + EPSV);
    sc3s[o] = sc;
    sh3s[o] = b3v[o] - mean * sc;
  }
  __syncthreads();
  for (int idx = t; idx < 8 * C2_; idx += 128) {
    int r = idx >> 8, o = idx & 255;
    float sc = sc3s[o];
    float v = sc >= 0.f ? Pmax[(row0 + r) * C2_ + o] : Pmin[(row0 + r) * C2_ + o];
    pooled[r][o] = lrelu(fmaf(sc, v, sh3s[o]));
  }
  __syncthreads();
  const float* w = w1 + t * C2_;
  float bias = b1v[t];
  float acc[8] = {bias, bias, bias, bias, bias, bias, bias, bias};
  for (int c = 0; c < C2_; c += 4) {
    float4 wv = *(const float4*)(w + c);
#pragma unroll
    for (int r = 0; r < 8; ++r) {
      float4 pv = *(const float4*)(&pooled[r][c]);
      acc[r] = fmaf(wv.x, pv.x, fmaf(wv.y, pv.y, fmaf(wv.z, pv.z, fmaf(wv.w, pv.w, acc[r]))));
    }
  }
  float s = 0.f, s2 = 0.f;
#pragma unroll
  for (int r = 0; r < 8; ++r) {
    X4[(row0 + r) * H_ + t] = acc[r];
    s += acc[r]; s2 = fmaf(acc[r], acc[r], s2);
  }
  atomicAdd(&sum4[t], s);
  atomicAdd(&ssq4[t], s2);
}

// ---------------- bn4+relu + fc2 (+stats5), inline bn4, 8 rows/block ----------------
__global__ __launch_bounds__(64) void k_fc2(const float* __restrict__ X4,
                                            const float* __restrict__ sum4,
                                            const float* __restrict__ ssq4,
                                            const float* __restrict__ g4v,
                                            const float* __restrict__ b4v,
                                            const float* __restrict__ w2,
                                            const float* __restrict__ b2v,
                                            float* __restrict__ X5,
                                            float* __restrict__ sum5,
                                            float* __restrict__ ssq5) {
  __shared__ float y[8][H_];
  __shared__ float sc4s[H_], sh4s[H_];
  int row0 = blockIdx.x * 8, t = threadIdx.x;
  for (int j = t; j < H_; j += 64) {
    float mean = sum4[j] / CNT45;
    float var = ssq4[j] / CNT45 - mean * mean;
    float sc = g4v[j] * rsqrtf(var + EPSV);
    sc4s[j] = sc;
    sh4s[j] = b4v[j] - mean * sc;
  }
  __syncthreads();
  for (int idx = t; idx < 8 * H_; idx += 64) {
    int r = idx >> 7, j = idx & 127;
    float x = fmaf(sc4s[j], X4[(row0 + r) * H_ + j], sh4s[j]);
    y[r][j] = x > 0.f ? x : 0.f;
  }
  __syncthreads();
  const float* w = w2 + t * H_;
  float bias = b2v[t];
  float acc[8] = {bias, bias, bias, bias, bias, bias, bias, bias};
  for (int c = 0; c < H_; c += 4) {
    float4 wv = *(const float4*)(w + c);
#pragma unroll
    for (int r = 0; r < 8; ++r) {
      float4 yv = *(const float4*)(&y[r][c]);
      acc[r] = fmaf(wv.x, yv.x, fmaf(wv.y, yv.y, fmaf(wv.z, yv.z, fmaf(wv.w, yv.w, acc[r]))));
    }
  }
  float s = 0.f, s2 = 0.f;
#pragma unroll
  for (int r = 0; r < 8; ++r) {
    X5[(row0 + r) * O_ + t] = acc[r];
    s += acc[r]; s2 = fmaf(acc[r], acc[r], s2);
  }
  atomicAdd(&sum5[t], s);
  atomicAdd(&ssq5[t], s2);
}

// ---------------- bn5 + relu -> out (inline bn5) ----------------
__global__ __launch_bounds__(256) void k_out(const float* __restrict__ X5,
                                             const float* __restrict__ sum5,
                                             const float* __restrict__ ssq5,
                                             const float* __restrict__ g5v,
                                             const float* __restrict__ b5v,
                                             float* __restrict__ out) {
  __shared__ float sc5s[O_], sh5s[O_];
  int t = threadIdx.x;
  if (t < O_) {
    float mean = sum5[t] / CNT45;
    float var = ssq5[t] / CNT45 - mean * mean;
    float sc = g5v[t] * rsqrtf(var + EPSV);
    sc5s[t] = sc;
    sh5s[t] = b5v[t] - mean * sc;
  }
  __syncthreads();
  int i = blockIdx.x * 256 + t;
  float x = fmaf(sc5s[i & (O_ - 1)], X5[i], sh5s[i & (O_ - 1)]);
  out[i] = x > 0.f ? x : 0.f;
}

// ---------------- launch ----------------
extern "C" void kernel_launch(void* const* d_in, const int* in_sizes, int n_in,
                              void* d_out, int out_size, void* d_ws, size_t ws_size,
                              hipStream_t stream) {
  const float* pf   = (const float*)d_in[0];
  const float* cf   = (const float*)d_in[1];
  const float* W1   = (const float*)d_in[2];
  const float* g1   = (const float*)d_in[3];
  const float* b1   = (const float*)d_in[4];
  const float* W2   = (const float*)d_in[5];
  const float* g2   = (const float*)d_in[6];
  const float* b2   = (const float*)d_in[7];
  const float* W3   = (const float*)d_in[8];
  const float* g3   = (const float*)d_in[9];
  const float* b3   = (const float*)d_in[10];
  const float* fc1w = (const float*)d_in[11];
  const float* fc1b = (const float*)d_in[12];
  const float* g4   = (const float*)d_in[13];
  const float* b4   = (const float*)d_in[14];
  const float* fc2w = (const float*)d_in[15];
  const float* fc2b = (const float*)d_in[16];
  const float* g5   = (const float*)d_in[17];
  const float* b5   = (const float*)d_in[18];
  float* ws  = (float*)d_ws;
  float* out = (float*)d_out;
  ushort* w2b = (ushort*)(ws + WS_W2BF);
  ushort* w3b = (ushort*)(ws + WS_W3BF);

  hipMemsetAsync(ws + WS_ZERO_BEG, 0, WS_ZERO_CNT * sizeof(float), stream);

  k_cvtW<<<(C2_ * C2_) / 256, 256, 0, stream>>>(W2, W3, w2b, w3b);
  k_proj4<<<B_ * N_ / 4, 128, 0, stream>>>(pf, W1, ws + WS_H1, 0);
  k_proj4<<<B_ * M_ / 4, 128, 0, stream>>>(cf, W1, ws + WS_HC, C_);
  k_rowstats<<<(B_ * N_) / 32, 256, 0, stream>>>(ws + WS_H1, ws + WS_SUMA, ws + WS_SSQA, N_);
  k_rowstats<<<(B_ * M_) / 32, 256, 0, stream>>>(ws + WS_HC, ws + WS_SUMC, ws + WS_SSQC, M_);
  k_x2f<<<B_ * N_ / 2, 512, 0, stream>>>(ws + WS_H1, ws + WS_HC,
                                         ws + WS_SUMA, ws + WS_SSQA, ws + WS_SUMC, ws + WS_SSQC,
                                         g1, b1, w2b, ws + WS_SUM2, ws + WS_SSQ2);
  k_x3f<<<B_ * N_ / 2, 512, 0, stream>>>(ws + WS_H1, ws + WS_HC,
                                         ws + WS_SUMA, ws + WS_SSQA, ws + WS_SUMC, ws + WS_SSQC,
                                         g1, b1, w2b,
                                         ws + WS_SUM2, ws + WS_SSQ2, g2, b2, w3b,
                                         ws + WS_SUM3, ws + WS_SSQ3,
                                         ws + WS_PMAX, ws + WS_PMIN);
  k_fc1<<<B_ * N_ / 8, 128, 0, stream>>>(ws + WS_PMAX, ws + WS_PMIN,
                                         ws + WS_SUM3, ws + WS_SSQ3, g3, b3,
                                         fc1w, fc1b, ws + WS_X4, ws + WS_SUM4, ws + WS_SSQ4);
  k_fc2<<<B_ * N_ / 8, 64, 0, stream>>>(ws + WS_X4, ws + WS_SUM4, ws + WS_SSQ4, g4, b4,
                                        fc2w, fc2b, ws + WS_X5, ws + WS_SUM5, ws + WS_SSQ5);
  k_out<<<(B_ * N_ * O_) / 256, 256, 0, stream>>>(ws + WS_X5, ws + WS_SUM5, ws + WS_SSQ5,
                                                  g5, b5, out);
}

// Round 13
// 235.835 us; speedup vs baseline: 2.0422x; 1.0294x over previous
//
#include <hip/hip_runtime.h>
#include <math.h>

#define EPSV   1e-5f
#define SLOPE  0.2f

#define B_   2
#define N_   2048
#define M_   64
#define C_   128
#define C2_  256
#define H_   128
#define O_   64

typedef short  s16x8  __attribute__((ext_vector_type(8)));
typedef ushort u16x8  __attribute__((ext_vector_type(8)));
typedef float  f32x16 __attribute__((ext_vector_type(16)));

#define ZERO16 {0.f,0.f,0.f,0.f,0.f,0.f,0.f,0.f,0.f,0.f,0.f,0.f,0.f,0.f,0.f,0.f}

// ---------------- workspace (float offsets) ----------------
#define WS_H1      0            // [4096*128]
#define WS_HC      524288       // [128*128]
#define WS_PMAX    540672       // [4096*256]
#define WS_PMIN    1589248      // [4096*256]
#define WS_W2BF    2637824      // 256*128 bf16
#define WS_W3BF    2654208      // 256*256 bf16
#define WS_SUMA    2686976      // [2*128]
#define WS_SSQA    2687232
#define WS_SUMC    2687488
#define WS_SSQC    2687744
#define WS_SUM2    2688000      // [256]
#define WS_SSQ2    2688256
#define WS_SUM3    2688512
#define WS_SSQ3    2688768
#define WS_SUM4    2689024      // [128]
#define WS_SSQ4    2689152
#define WS_SUM5    2689280      // [64]
#define WS_SSQ5    2689344
#define WS_ZERO_BEG WS_SUMA
#define WS_ZERO_CNT (2689408 - WS_SUMA)
#define WS_X4      WS_H1        // reuse (H1 dead after k_x3f)
#define WS_X5      WS_PMIN      // reuse (PMIN dead after k_fc1)

#define CNT1  ((float)B_ * N_ * M_)
#define CNT45 ((float)B_ * N_)

__device__ inline ushort f2b(float x) {
  unsigned u = __builtin_bit_cast(unsigned, x);
  u += 0x7fffu + ((u >> 16) & 1u);
  return (ushort)(u >> 16);
}
__device__ inline float lrelu(float x) { return fmaxf(x, SLOPE * x); }

// ---------------- W -> bf16 ----------------
__global__ __launch_bounds__(256) void k_cvtW(const float* __restrict__ W2,
                                              const float* __restrict__ W3,
                                              ushort* __restrict__ w2b,
                                              ushort* __restrict__ w3b) {
  int i = blockIdx.x * 256 + threadIdx.x;
  if (i < C2_ * C_) w2b[i] = f2b(W2[i]);
  w3b[i] = f2b(W3[i]);
}

// ---------------- projections, 4 rows/block ----------------
__global__ __launch_bounds__(128) void k_proj4(const float* __restrict__ x,
                                               const float* __restrict__ W1,
                                               float* __restrict__ out, int col_off) {
  __shared__ float xs[4][C_];
  int row0 = blockIdx.x * 4, t = threadIdx.x;
#pragma unroll
  for (int r = 0; r < 4; ++r) xs[r][t] = x[(row0 + r) * C_ + t];
  __syncthreads();
  const float* w = W1 + t * (2 * C_) + col_off;
  float acc[4] = {0.f, 0.f, 0.f, 0.f};
  for (int c = 0; c < C_; c += 4) {
    float4 wv = *(const float4*)(w + c);
#pragma unroll
    for (int r = 0; r < 4; ++r) {
      float4 xv = *(const float4*)(&xs[r][c]);
      acc[r] = fmaf(wv.x, xv.x, fmaf(wv.y, xv.y, fmaf(wv.z, xv.z, fmaf(wv.w, xv.w, acc[r]))));
    }
  }
#pragma unroll
  for (int r = 0; r < 4; ++r) out[(row0 + r) * C_ + t] = acc[r];
}

// ---------------- coalesced per-(b,c) row stats ----------------
__global__ __launch_bounds__(256) void k_rowstats(const float* __restrict__ x,
                                                  float* __restrict__ sums,
                                                  float* __restrict__ ssqs,
                                                  int rows_per_b) {
  __shared__ float red[256];
  int t = threadIdx.x, c = t & 127, rr = t >> 7;
  int r0 = blockIdx.x * 32, b = r0 / rows_per_b;
  float s = 0.f, s2 = 0.f;
  for (int i = 0; i < 16; ++i) {
    float v = x[(r0 + rr + i * 2) * C_ + c];
    s += v; s2 = fmaf(v, v, s2);
  }
  red[t] = s;
  __syncthreads();
  if (t < 128) atomicAdd(&sums[b * C_ + t], red[t] + red[t + 128]);
  __syncthreads();
  red[t] = s2;
  __syncthreads();
  if (t < 128) atomicAdd(&ssqs[b * C_ + t], red[t] + red[t + 128]);
}

// ---------------- build S1 tile: 128 rows (2 n x 64 m), inline bn1 ----------------
// S1 ushort idx: r*128 + ((j ^ (r&15))<<3) + (c&7),  j = c>>3
__device__ inline void build_S1_128(ushort* S1, const float* __restrict__ h1,
                                    const float* __restrict__ hc,
                                    const float* __restrict__ sumA,
                                    const float* __restrict__ ssqA,
                                    const float* __restrict__ sumC,
                                    const float* __restrict__ ssqC,
                                    const float* __restrict__ g1,
                                    const float* __restrict__ b1,
                                    int nf0, int b,
                                    float (*h1s)[C_], float* sc1, float* sh1) {
  int t = threadIdx.x;
  if (t < 256) h1s[t >> 7][t & 127] = h1[(nf0 + (t >> 7)) * C_ + (t & 127)];
  if (t < C_) {
    int c = t;
    float sA0 = sumA[c], sA1 = sumA[C_ + c], qA0 = ssqA[c], qA1 = ssqA[C_ + c];
    float sC0 = sumC[c], sC1 = sumC[C_ + c], qC0 = ssqC[c], qC1 = ssqC[C_ + c];
    float mean = ((float)M_ * (sA0 + sA1) + (float)N_ * (sC0 + sC1)) / CNT1;
    float ex2 = ((float)M_ * (qA0 + qA1) + (float)N_ * (qC0 + qC1)
                 + 2.f * (sA0 * sC0 + sA1 * sC1)) / CNT1;
    float var = ex2 - mean * mean;
    float sc = g1[c] * rsqrtf(var + EPSV);
    sc1[c] = sc;
    sh1[c] = b1[c] - mean * sc;
  }
  __syncthreads();
  const float* hcb = hc + b * M_ * C_;
#pragma unroll
  for (int i = 0; i < 4; ++i) {          // 128 rows * 16 slots / 512 thr
    int s = t + i * 512;
    int r = s >> 4, j = s & 15, c0 = j << 3;
    const float* hr = h1s[r >> 6];
    const float* src = hcb + (r & 63) * C_ + c0;
    float4 v0 = *(const float4*)(src);
    float4 v1 = *(const float4*)(src + 4);
    u16x8 q;
    q[0] = f2b(lrelu(fmaf(sc1[c0+0], hr[c0+0] + v0.x, sh1[c0+0])));
    q[1] = f2b(lrelu(fmaf(sc1[c0+1], hr[c0+1] + v0.y, sh1[c0+1])));
    q[2] = f2b(lrelu(fmaf(sc1[c0+2], hr[c0+2] + v0.z, sh1[c0+2])));
    q[3] = f2b(lrelu(fmaf(sc1[c0+3], hr[c0+3] + v0.w, sh1[c0+3])));
    q[4] = f2b(lrelu(fmaf(sc1[c0+4], hr[c0+4] + v1.x, sh1[c0+4])));
    q[5] = f2b(lrelu(fmaf(sc1[c0+5], hr[c0+5] + v1.y, sh1[c0+5])));
    q[6] = f2b(lrelu(fmaf(sc1[c0+6], hr[c0+6] + v1.z, sh1[c0+6])));
    q[7] = f2b(lrelu(fmaf(sc1[c0+7], hr[c0+7] + v1.w, sh1[c0+7])));
    *(u16x8*)(S1 + r * C_ + ((j ^ (r & 15)) << 3)) = q;
  }
  __syncthreads();
}

// ---------------- pass B: stats of X2 (128-row block, 8 col-groups, 2 accs) ----------------
__global__ __launch_bounds__(512, 2) void k_x2f(const float* __restrict__ h1,
                                                const float* __restrict__ hc,
                                                const float* __restrict__ sumA,
                                                const float* __restrict__ ssqA,
                                                const float* __restrict__ sumC,
                                                const float* __restrict__ ssqC,
                                                const float* __restrict__ g1v,
                                                const float* __restrict__ b1v,
                                                const ushort* __restrict__ W2b,
                                                float* __restrict__ sum2,
                                                float* __restrict__ ssq2) {
  __shared__ __align__(16) ushort S1[128 * C_];   // 32 KB
  __shared__ float h1s[2][C_], sc1[C_], sh1[C_];
  int nf0 = blockIdx.x * 2, b = nf0 >> 11;
  build_S1_128(S1, h1, hc, sumA, ssqA, sumC, ssqC, g1v, b1v, nf0, b, h1s, sc1, sh1);
  int t = threadIdx.x, wv = t >> 6, lane = t & 63, l31 = lane & 31, l5 = lane >> 5;
  int col = wv * 32 + l31;
  const ushort* wr = W2b + col * C_ + l5 * 8;
  float sm = 0.f, sq = 0.f;

#pragma unroll 1
  for (int h = 0; h < 2; ++h) {
    f32x16 acc0 = ZERO16, acc1 = ZERO16;
    int r0 = h * 64 + l31, r1 = r0 + 32;
    const ushort* s1r0 = S1 + r0 * C_;
    const ushort* s1r1 = S1 + r1 * C_;
    int rx0 = r0 & 15, rx1 = r1 & 15;
#pragma unroll
    for (int ks = 0; ks < 8; ++ks) {
      int j = ks * 2 + l5;
      s16x8 bv = *(const s16x8*)(wr + ks * 16);
      s16x8 a0 = *(const s16x8*)(s1r0 + ((j ^ rx0) << 3));
      s16x8 a1 = *(const s16x8*)(s1r1 + ((j ^ rx1) << 3));
      acc0 = __builtin_amdgcn_mfma_f32_32x32x16_bf16(a0, bv, acc0, 0, 0, 0);
      acc1 = __builtin_amdgcn_mfma_f32_32x32x16_bf16(a1, bv, acc1, 0, 0, 0);
    }
#pragma unroll
    for (int rg = 0; rg < 16; ++rg) {
      float v;
      v = acc0[rg]; sm += v; sq = fmaf(v, v, sq);
      v = acc1[rg]; sm += v; sq = fmaf(v, v, sq);
    }
  }
  sm += __shfl_xor(sm, 32); sq += __shfl_xor(sq, 32);
  if (lane < 32) {
    atomicAdd(&sum2[col], sm);
    atomicAdd(&ssq2[col], sq);
  }
}

// ---------------- pass C: stage2(T) + stage3 + pool (128-row block, 2 blocks/CU) ----------
// stage2 TRANSPOSED: A=W2-frag, B=S1-frag (same loads as before, swapped MFMA args).
// D2[o][m]: lane holds col m=l31 (+32 acc1), regs hold consecutive o -> pair-pack
// via v_cvt_pk_bf16_f32 + ds_write_b32 (halves epilogue stores + VALU).
// S2 ushort idx: r*256 + ((jo ^ (r&31))<<3) + (o&7), jo = o>>3  (unchanged layout)
__global__ __launch_bounds__(512, 2) void k_x3f(const float* __restrict__ h1,
                                                const float* __restrict__ hc,
                                                const float* __restrict__ sumA,
                                                const float* __restrict__ ssqA,
                                                const float* __restrict__ sumC,
                                                const float* __restrict__ ssqC,
                                                const float* __restrict__ g1v,
                                                const float* __restrict__ b1v,
                                                const ushort* __restrict__ W2b,
                                                const float* __restrict__ sum2,
                                                const float* __restrict__ ssq2,
                                                const float* __restrict__ g2v,
                                                const float* __restrict__ b2v,
                                                const ushort* __restrict__ W3b,
                                                float* __restrict__ sum3,
                                                float* __restrict__ ssq3,
                                                float* __restrict__ Pmax,
                                                float* __restrict__ Pmin) {
  __shared__ __align__(16) ushort S1[128 * C_];    // 32 KB
  __shared__ __align__(16) ushort S2[64 * C2_];    // 32 KB (one 64-row half)
  __shared__ float h1s[2][C_], sc1[C_], sh1[C_];
  __shared__ float sc2s[C2_], sh2s[C2_];
  int nf0 = blockIdx.x * 2, b = nf0 >> 11;
  int t = threadIdx.x;
  if (t < C2_) {   // inline bn2 params
    float mean = sum2[t] / CNT1;
    float var = ssq2[t] / CNT1 - mean * mean;
    float sc = g2v[t] * rsqrtf(var + EPSV);
    sc2s[t] = sc;
    sh2s[t] = b2v[t] - mean * sc;
  }
  build_S1_128(S1, h1, hc, sumA, ssqA, sumC, ssqC, g1v, b1v, nf0, b, h1s, sc1, sh1);
  int wv = t >> 6, lane = t & 63, l31 = lane & 31, l5 = lane >> 5;
  int col = wv * 32 + l31;     // stage2: A-row o ; stage3: output col o
  int OBw = wv * 32;
  const ushort* w2r = W2b + col * C_ + l5 * 8;
  const ushort* w3r = W3b + col * C2_ + l5 * 8;
  float sm = 0.f, sq = 0.f;

#pragma unroll 1
  for (int h = 0; h < 2; ++h) {
    // ---- stage 2 (transposed D): 64 m-rows x wave's 32 o -> S2
    {
      f32x16 acc0 = ZERO16, acc1 = ZERO16;   // D[o-rows][m=l31], m+32
      int r0 = h * 64 + l31, r1 = r0 + 32;
      const ushort* s1r0 = S1 + r0 * C_;
      const ushort* s1r1 = S1 + r1 * C_;
      int rx0 = r0 & 15, rx1 = r1 & 15;
#pragma unroll
      for (int ks = 0; ks < 8; ++ks) {
        int j = ks * 2 + l5;
        s16x8 aW = *(const s16x8*)(w2r + ks * 16);              // A = W2 (row o)
        s16x8 bS0 = *(const s16x8*)(s1r0 + ((j ^ rx0) << 3));   // B = S1 (col m)
        s16x8 bS1 = *(const s16x8*)(s1r1 + ((j ^ rx1) << 3));
        acc0 = __builtin_amdgcn_mfma_f32_32x32x16_bf16(aW, bS0, acc0, 0, 0, 0);
        acc1 = __builtin_amdgcn_mfma_f32_32x32x16_bf16(aW, bS1, acc1, 0, 0, 0);
      }
      // epilogue: bn2+lrelu, pack o-pairs, ds_write_b32
      int m0 = l31, m1 = l31 + 32;           // S2 local rows
      ushort* s2w0 = S2 + m0 * C2_;
      ushort* s2w1 = S2 + m1 * C2_;
      int mx0 = m0 & 31, mx1 = m1 & 31;
#pragma unroll
      for (int rg = 0; rg < 16; rg += 2) {
        int rp = (rg & 3) + 8 * (rg >> 2) + 4 * l5;
        int o = OBw + rp;                    // even; pair = (o, o+1)
        float scA = sc2s[o],     shA = sh2s[o];
        float scB = sc2s[o + 1], shB = sh2s[o + 1];
        float xe0 = lrelu(fmaf(scA, acc0[rg],     shA));
        float xo0 = lrelu(fmaf(scB, acc0[rg + 1], shB));
        float xe1 = lrelu(fmaf(scA, acc1[rg],     shA));
        float xo1 = lrelu(fmaf(scB, acc1[rg + 1], shB));
        unsigned p0, p1;
        asm("v_cvt_pk_bf16_f32 %0, %1, %2" : "=v"(p0) : "v"(xe0), "v"(xo0));
        asm("v_cvt_pk_bf16_f32 %0, %1, %2" : "=v"(p1) : "v"(xe1), "v"(xo1));
        int jo = o >> 3, ol = o & 7;
        *(unsigned*)(s2w0 + ((jo ^ mx0) << 3) + ol) = p0;
        *(unsigned*)(s2w1 + ((jo ^ mx1) << 3) + ol) = p1;
      }
    }
    __syncthreads();   // S2 half ready

    // ---- stage 3 (normal orientation): X3 = S2 . W3^T ; in-register pool over m
    {
      f32x16 acc0 = ZERO16, acc1 = ZERO16;
      const ushort* s2r0 = S2 + l31 * C2_;
      const ushort* s2r1 = S2 + (l31 + 32) * C2_;
#pragma unroll
      for (int ks = 0; ks < 16; ++ks) {
        int j3 = ks * 2 + l5;
        s16x8 bv = *(const s16x8*)(w3r + ks * 16);
        s16x8 a0 = *(const s16x8*)(s2r0 + ((j3 ^ l31) << 3));
        s16x8 a1 = *(const s16x8*)(s2r1 + ((j3 ^ l31) << 3));
        acc0 = __builtin_amdgcn_mfma_f32_32x32x16_bf16(a0, bv, acc0, 0, 0, 0);
        acc1 = __builtin_amdgcn_mfma_f32_32x32x16_bf16(a1, bv, acc1, 0, 0, 0);
      }
      float pmx = -3.4e38f, pmn = 3.4e38f;
#pragma unroll
      for (int rg = 0; rg < 16; ++rg) {
        float v;
        v = acc0[rg]; pmx = fmaxf(pmx, v); pmn = fminf(pmn, v); sm += v; sq = fmaf(v, v, sq);
        v = acc1[rg]; pmx = fmaxf(pmx, v); pmn = fminf(pmn, v); sm += v; sq = fmaf(v, v, sq);
      }
      pmx = fmaxf(pmx, __shfl_xor(pmx, 32));
      pmn = fminf(pmn, __shfl_xor(pmn, 32));
      int nf = nf0 + h;
      if (lane < 32) {
        Pmax[nf * C2_ + col] = pmx;
        Pmin[nf * C2_ + col] = pmn;
      }
    }
    __syncthreads();   // stage3 reads done before next half overwrites S2
  }
  sm += __shfl_xor(sm, 32); sq += __shfl_xor(sq, 32);
  if (lane < 32) {
    atomicAdd(&sum3[col], sm);
    atomicAdd(&ssq3[col], sq);
  }
}

// ---------------- pool-select + fc1 (+stats4), inline bn3, 8 rows/block ----------------
__global__ __launch_bounds__(128) void k_fc1(const float* __restrict__ Pmax,
                                             const float* __restrict__ Pmin,
                                             const float* __restrict__ sum3,
                                             const float* __restrict__ ssq3,
                                             const float* __restrict__ g3v,
                                             const float* __restrict__ b3v,
                                             const float* __restrict__ w1,
                                             const float* __restrict__ b1v,
                                             float* __restrict__ X4,
                                             float* __restrict__ sum4,
                                             float* __restrict__ ssq4) {
  __shared__ float pooled[8][C2_];
  __shared__ float sc3s[C2_], sh3s[C2_];
  int row0 = blockIdx.x * 8, t = threadIdx.x;
  for (int o = t; o < C2_; o += 128) {
    float mean = sum3[o] / CNT1;
    float var = ssq3[o] / CNT1 - mean * mean;
    float sc = g3v[o] * rsqrtf(var + EPSV);
    sc3s[o] = sc;
    sh3s[o] = b3v[o] - mean * sc;
  }
  __syncthreads();
  for (int idx = t; idx < 8 * C2_; idx += 128) {
    int r = idx >> 8, o = idx & 255;
    float sc = sc3s[o];
    float v = sc >= 0.f ? Pmax[(row0 + r) * C2_ + o] : Pmin[(row0 + r) * C2_ + o];
    pooled[r][o] = lrelu(fmaf(sc, v, sh3s[o]));
  }
  __syncthreads();
  const float* w = w1 + t * C2_;
  float bias = b1v[t];
  float acc[8] = {bias, bias, bias, bias, bias, bias, bias, bias};
  for (int c = 0; c < C2_; c += 4) {
    float4 wv = *(const float4*)(w + c);
#pragma unroll
    for (int r = 0; r < 8; ++r) {
      float4 pv = *(const float4*)(&pooled[r][c]);
      acc[r] = fmaf(wv.x, pv.x, fmaf(wv.y, pv.y, fmaf(wv.z, pv.z, fmaf(wv.w, pv.w, acc[r]))));
    }
  }
  float s = 0.f, s2 = 0.f;
#pragma unroll
  for (int r = 0; r < 8; ++r) {
    X4[(row0 + r) * H_ + t] = acc[r];
    s += acc[r]; s2 = fmaf(acc[r], acc[r], s2);
  }
  atomicAdd(&sum4[t], s);
  atomicAdd(&ssq4[t], s2);
}

// ---------------- bn4+relu + fc2 (+stats5), inline bn4, 8 rows/block ----------------
__global__ __launch_bounds__(64) void k_fc2(const float* __restrict__ X4,
                                            const float* __restrict__ sum4,
                                            const float* __restrict__ ssq4,
                                            const float* __restrict__ g4v,
                                            const float* __restrict__ b4v,
                                            const float* __restrict__ w2,
                                            const float* __restrict__ b2v,
                                            float* __restrict__ X5,
                                            float* __restrict__ sum5,
                                            float* __restrict__ ssq5) {
  __shared__ float y[8][H_];
  __shared__ float sc4s[H_], sh4s[H_];
  int row0 = blockIdx.x * 8, t = threadIdx.x;
  for (int j = t; j < H_; j += 64) {
    float mean = sum4[j] / CNT45;
    float var = ssq4[j] / CNT45 - mean * mean;
    float sc = g4v[j] * rsqrtf(var + EPSV);
    sc4s[j] = sc;
    sh4s[j] = b4v[j] - mean * sc;
  }
  __syncthreads();
  for (int idx = t; idx < 8 * H_; idx += 64) {
    int r = idx >> 7, j = idx & 127;
    float x = fmaf(sc4s[j], X4[(row0 + r) * H_ + j], sh4s[j]);
    y[r][j] = x > 0.f ? x : 0.f;
  }
  __syncthreads();
  const float* w = w2 + t * H_;
  float bias = b2v[t];
  float acc[8] = {bias, bias, bias, bias, bias, bias, bias, bias};
  for (int c = 0; c < H_; c += 4) {
    float4 wv = *(const float4*)(w + c);
#pragma unroll
    for (int r = 0; r < 8; ++r) {
      float4 yv = *(const float4*)(&y[r][c]);
      acc[r] = fmaf(wv.x, yv.x, fmaf(wv.y, yv.y, fmaf(wv.z, yv.z, fmaf(wv.w, yv.w, acc[r]))));
    }
  }
  float s = 0.f, s2 = 0.f;
#pragma unroll
  for (int r = 0; r < 8; ++r) {
    X5[(row0 + r) * O_ + t] = acc[r];
    s += acc[r]; s2 = fmaf(acc[r], acc[r], s2);
  }
  atomicAdd(&sum5[t], s);
  atomicAdd(&ssq5[t], s2);
}

// ---------------- bn5 + relu -> out (inline bn5) ----------------
__global__ __launch_bounds__(256) void k_out(const float* __restrict__ X5,
                                             const float* __restrict__ sum5,
                                             const float* __restrict__ ssq5,
                                             const float* __restrict__ g5v,
                                             const float* __restrict__ b5v,
                                             float* __restrict__ out) {
  __shared__ float sc5s[O_], sh5s[O_];
  int t = threadIdx.x;
  if (t < O_) {
    float mean = sum5[t] / CNT45;
    float var = ssq5[t] / CNT45 - mean * mean;
    float sc = g5v[t] * rsqrtf(var + EPSV);
    sc5s[t] = sc;
    sh5s[t] = b5v[t] - mean * sc;
  }
  __syncthreads();
  int i = blockIdx.x * 256 + t;
  float x = fmaf(sc5s[i & (O_ - 1)], X5[i], sh5s[i & (O_ - 1)]);
  out[i] = x > 0.f ? x : 0.f;
}

// ---------------- launch ----------------
extern "C" void kernel_launch(void* const* d_in, const int* in_sizes, int n_in,
                              void* d_out, int out_size, void* d_ws, size_t ws_size,
                              hipStream_t stream) {
  const float* pf   = (const float*)d_in[0];
  const float* cf   = (const float*)d_in[1];
  const float* W1   = (const float*)d_in[2];
  const float* g1   = (const float*)d_in[3];
  const float* b1   = (const float*)d_in[4];
  const float* W2   = (const float*)d_in[5];
  const float* g2   = (const float*)d_in[6];
  const float* b2   = (const float*)d_in[7];
  const float* W3   = (const float*)d_in[8];
  const float* g3   = (const float*)d_in[9];
  const float* b3   = (const float*)d_in[10];
  const float* fc1w = (const float*)d_in[11];
  const float* fc1b = (const float*)d_in[12];
  const float* g4   = (const float*)d_in[13];
  const float* b4   = (const float*)d_in[14];
  const float* fc2w = (const float*)d_in[15];
  const float* fc2b = (const float*)d_in[16];
  const float* g5   = (const float*)d_in[17];
  const float* b5   = (const float*)d_in[18];
  float* ws  = (float*)d_ws;
  float* out = (float*)d_out;
  ushort* w2b = (ushort*)(ws + WS_W2BF);
  ushort* w3b = (ushort*)(ws + WS_W3BF);

  hipMemsetAsync(ws + WS_ZERO_BEG, 0, WS_ZERO_CNT * sizeof(float), stream);

  k_cvtW<<<(C2_ * C2_) / 256, 256, 0, stream>>>(W2, W3, w2b, w3b);
  k_proj4<<<B_ * N_ / 4, 128, 0, stream>>>(pf, W1, ws + WS_H1, 0);
  k_proj4<<<B_ * M_ / 4, 128, 0, stream>>>(cf, W1, ws + WS_HC, C_);
  k_rowstats<<<(B_ * N_) / 32, 256, 0, stream>>>(ws + WS_H1, ws + WS_SUMA, ws + WS_SSQA, N_);
  k_rowstats<<<(B_ * M_) / 32, 256, 0, stream>>>(ws + WS_HC, ws + WS_SUMC, ws + WS_SSQC, M_);
  k_x2f<<<B_ * N_ / 2, 512, 0, stream>>>(ws + WS_H1, ws + WS_HC,
                                         ws + WS_SUMA, ws + WS_SSQA, ws + WS_SUMC, ws + WS_SSQC,
                                         g1, b1, w2b, ws + WS_SUM2, ws + WS_SSQ2);
  k_x3f<<<B_ * N_ / 2, 512, 0, stream>>>(ws + WS_H1, ws + WS_HC,
                                         ws + WS_SUMA, ws + WS_SSQA, ws + WS_SUMC, ws + WS_SSQC,
                                         g1, b1, w2b,
                                         ws + WS_SUM2, ws + WS_SSQ2, g2, b2, w3b,
                                         ws + WS_SUM3, ws + WS_SSQ3,
                                         ws + WS_PMAX, ws + WS_PMIN);
  k_fc1<<<B_ * N_ / 8, 128, 0, stream>>>(ws + WS_PMAX, ws + WS_PMIN,
                                         ws + WS_SUM3, ws + WS_SSQ3, g3, b3,
                                         fc1w, fc1b, ws + WS_X4, ws + WS_SUM4, ws + WS_SSQ4);
  k_fc2<<<B_ * N_ / 8, 64, 0, stream>>>(ws + WS_X4, ws + WS_SUM4, ws + WS_SSQ4, g4, b4,
                                        fc2w, fc2b, ws + WS_X5, ws + WS_SUM5, ws + WS_SSQ5);
  k_out<<<(B_ * N_ * O_) / 256, 256, 0, stream>>>(ws + WS_X5, ws + WS_SUM5, ws + WS_SSQ5,
                                                  g5, b5, out);
}